// Round 4
// baseline (843.185 us; speedup 1.0000x reference)
//
#include <hip/hip_runtime.h>
#include <math.h>

#define NB    4096
#define NH    128
#define NKIN  8
#define NKOUT 4
#define NTP   64
#define NL    128
#define BKIN  (NB*NKIN)
#define LOG2E 1.44269504088896340736f

typedef __attribute__((ext_vector_type(8))) short short8;
typedef __attribute__((ext_vector_type(4))) float f32x4;

#if __has_builtin(__builtin_amdgcn_exp2f)
#define EXP2F __builtin_amdgcn_exp2f
#else
#define EXP2F exp2f
#endif

__device__ __forceinline__ short f2bf(float f) {
    union { float f; unsigned u; } v; v.f = f;
    unsigned u = v.u;
    return (short)((u + 0x7fffu + ((u >> 16) & 1u)) >> 16);
}
__device__ __forceinline__ unsigned pkbf2(float a, float b) {
#if __has_builtin(__builtin_amdgcn_cvt_pk_bf16_f32)
    auto p = __builtin_amdgcn_cvt_pk_bf16_f32(a, b);
    unsigned q; __builtin_memcpy(&q, &p, 4); return q;
#else
    union { float f; unsigned u; } x, y; x.f = a; y.f = b;
    unsigned ua = (x.u + 0x7fffu + ((x.u >> 16) & 1u)) >> 16;
    unsigned ub = (y.u + 0x7fffu + ((y.u >> 16) & 1u)) & 0xffff0000u;
    return ua | ub;
#endif
}
__device__ __forceinline__ void st4(short* dst, const f32x4& v) {
    uint2 q; q.x = pkbf2(v[0], v[1]); q.y = pkbf2(v[2], v[3]);
    *(uint2*)dst = q;
}
__device__ __forceinline__ float tanh2(float a2) {   // tanh given pre-scaled 2*log2e*x
    return 1.0f - 2.0f*__builtin_amdgcn_rcpf(1.0f + EXP2F(a2));
}

// ---------------- spline: Thomas solve -> UM (midpoint control values) ----
__global__ void spline_um_kernel(const float* __restrict__ pre_x,
                                 const float* __restrict__ fx,
                                 float* __restrict__ UM)
{
    __shared__ float cp[128];
    if (threadIdx.x == 0) {
        float c = 0.f;
        for (int j = 1; j <= 127; ++j) { c = 1.0f/(4.0f - c); cp[j] = c; }
    }
    __syncthreads();
    int col = blockIdx.x*128 + threadIdx.x;
    const float r6 = 6.0f/(0.1f*0.1f);
    const float KK = 0.01f/16.0f;   // hs^2/16
    float y0 = pre_x[(size_t)(NTP-1)*BKIN + col];
    float y1 = fx[col];
    float d = 0.f;
    for (int j = 1; j <= 127; ++j) {
        float y2 = fx[(size_t)j*BKIN + col];
        float r  = r6*(y0 - 2.f*y1 + y2);
        d = (r - d)*cp[j];
        UM[(size_t)j*BKIN + col] = d;
        y0 = y1; y1 = y2;
    }
    float xn  = 0.f;
    float yj1 = fx[(size_t)127*BKIN + col];
    for (int j = 127; j >= 1; --j) {
        float dj = UM[(size_t)j*BKIN + col];
        float x  = dj - cp[j]*xn;                    // M_j
        float yj = fx[(size_t)(j-1)*BKIN + col];
        UM[(size_t)j*BKIN + col] = 0.5f*(yj + yj1) - KK*(x + xn);
        xn = x; yj1 = yj;
    }
    float ys0 = pre_x[(size_t)(NTP-1)*BKIN + col];
    UM[col] = 0.5f*(ys0 + yj1) - KK*xn;
}

// ---------------- prep: W1/W2 as A-operand fragments (bf16, W1 pre-scaled) ----
__global__ void prep_frags(const float* __restrict__ W1, const float* __restrict__ W2,
                           short* __restrict__ w1f, short* __restrict__ w2f)
{
    int tid = threadIdx.x;
    for (int idx = tid; idx < 16*4*64*8; idx += 256) {
        int j = idx & 7, lane = (idx >> 3) & 63, kc = (idx >> 9) & 3, t = idx >> 11;
        int row = t*16 + (lane & 15);
        int k   = kc*32 + (lane >> 4)*8 + j;
        w1f[idx] = f2bf(2.0f*LOG2E*W1[row*NH + k]);
    }
    for (int idx = tid; idx < 8*64*8; idx += 256) {
        int j = idx & 7, lane = (idx >> 3) & 63, kc = idx >> 9;
        int m = lane & 15;
        int k = kc*32 + (lane >> 4)*8 + j;
        w2f[idx] = (m < NKOUT) ? f2bf(W2[m*2*NH + k]) : (short)0;
    }
}

// ---------------- fused kernel helpers ----------------
__device__ __forceinline__ void gemmB(const short* bp, const short8 (&A)[3][4], f32x4 (&acc)[3])
{
    #pragma unroll
    for (int kc = 0; kc < 4; ++kc) {
        short8 b = *(const short8*)(bp + kc*32);
        #pragma unroll
        for (int g = 0; g < 3; ++g)
            acc[g] = __builtin_amdgcn_mfma_f32_16x16x32_bf16(A[g][kc], b, acc[g], 0, 0, 0);
    }
}
__device__ __forceinline__ void gateK(const f32x4 (&gi)[3], const f32x4 (&gh)[3],
                                      const f32x4& yin, f32x4& K)
{
    #pragma unroll
    for (int r = 0; r < 4; ++r) {
        float rg = __builtin_amdgcn_rcpf(1.0f + EXP2F(gi[0][r] + gh[0][r]));
        float zg = __builtin_amdgcn_rcpf(1.0f + EXP2F(gi[1][r] + gh[1][r]));
        float tg = tanh2(gi[2][r] + rg*gh[2][r]);
        K[r] = (1.0f - zg)*(tg - yin[r]);
    }
}

__global__ void __launch_bounds__(512, 2)
fused_kernel(const float* __restrict__ pre_x, const float* __restrict__ pre_y,
             const float* __restrict__ fx,
             const float* __restrict__ W_ih, const float* __restrict__ W_hh,
             const float* __restrict__ b_ih, const float* __restrict__ b_hh,
             const float* __restrict__ W_e,  const float* __restrict__ b_e,
             const float* __restrict__ Wc_ih,const float* __restrict__ Wc_hh,
             const float* __restrict__ bc_ih,const float* __restrict__ bc_hh,
             const float* __restrict__ UM,   const short* __restrict__ w1f,
             const short* __restrict__ w2f,  float* __restrict__ out)
{
    __shared__ __align__(16) short yTa[16*136];   // state ping / RK4 y
    __shared__ __align__(16) short yTb[16*136];   // state pong / RK4 E0
    __shared__ __align__(16) short E1 [16*136];
    __shared__ __align__(16) short xmT[16*136];
    __shared__ __align__(16) short x1T[16*136];
    __shared__ __align__(16) short UMb[16*40];    // enc input ping / RK4 um
    __shared__ __align__(16) short U1b[16*40];    // enc input pong / RK4 u1
    __shared__ __align__(16) short oT [16*264];

    const int tid  = threadIdx.x;
    const int w    = tid >> 6;
    const int lane = tid & 63;
    const int quad = lane >> 4;
    const int m    = lane & 15;
    const int hq   = w*16 + quad*4;
    const int b0   = blockIdx.x * 16;
    const f32x4 z4 = {0.f, 0.f, 0.f, 0.f};
    const float scg[3] = {-LOG2E, -LOG2E, 2.0f*LOG2E};

    for (int i = tid; i < 16*136; i += 512) yTa[i] = 0;
    for (int i = tid; i < 16*40;  i += 512) { UMb[i] = 0; U1b[i] = 0; }

    f32x4 y = z4;

    // ================= encoder GRU: 1 barrier/step (ping-pong) =================
    {
        short8 Ehh[3][4];
        #pragma unroll
        for (int g = 0; g < 3; ++g)
            #pragma unroll
            for (int c = 0; c < 4; ++c) {
                const float* ph = W_hh + (size_t)(g*NH + w*16 + m)*NH + c*32 + quad*8;
                short8 fh;
                #pragma unroll
                for (int j = 0; j < 8; ++j) fh[j] = f2bf(scg[g]*ph[j]);
                Ehh[g][c] = fh;
            }
        short8 Eih[3];
        #pragma unroll
        for (int g = 0; g < 3; ++g) {
            short8 f1;
            #pragma unroll
            for (int j = 0; j < 8; ++j) {
                int k = quad*8 + j;
                f1[j] = (k < 12) ? f2bf(scg[g]*W_ih[(size_t)(g*NH + w*16 + m)*12 + k]) : (short)0;
            }
            Eih[g] = f1;
        }
        f32x4 erz4, ezz4, egn4, ein4;
        #pragma unroll
        for (int r = 0; r < 4; ++r) {
            int h = hq + r;
            erz4[r] = -LOG2E*(b_ih[h]      + b_hh[h]);
            ezz4[r] = -LOG2E*(b_ih[NH + h] + b_hh[NH + h]);
            egn4[r] = 2.0f*LOG2E*b_hh[2*NH + h];
            ein4[r] = 2.0f*LOG2E*b_ih[2*NH + h];
        }
        const int eb = tid / 12, ek = tid - eb*12;
        float encv = 0.f;
        if (tid < 192) {
            float e0 = (ek < NKIN) ? pre_x[((size_t)0*NB + b0 + eb)*NKIN + ek]
                                   : pre_y[((size_t)0*NB + b0 + eb)*NKOUT + (ek - NKIN)];
            UMb[eb*40 + ek] = f2bf(e0);
            encv = (ek < NKIN) ? pre_x[((size_t)1*NB + b0 + eb)*NKIN + ek]
                               : pre_y[((size_t)1*NB + b0 + eb)*NKOUT + (ek - NKIN)];
        }
        __syncthreads();
        for (int t = 0; t < NTP; ++t) {
            float evn = 0.f;
            if (tid < 192) {                      // prefetch input(t+2) at window top
                int tn = (t + 2 < NTP) ? t + 2 : NTP - 1;
                evn = (ek < NKIN) ? pre_x[((size_t)tn*NB + b0 + eb)*NKIN + ek]
                                  : pre_y[((size_t)tn*NB + b0 + eb)*NKOUT + (ek - NKIN)];
            }
            const short* bin_buf  = (t & 1) ? U1b : UMb;
            short*       bout_buf = (t & 1) ? UMb : U1b;
            const short* sin_buf  = (t & 1) ? yTb : yTa;
            short*       sout_buf = (t & 1) ? yTa : yTb;
            f32x4 gi[3] = {z4, z4, ein4};
            {
                short8 b = *(const short8*)(bin_buf + m*40 + quad*8);
                #pragma unroll
                for (int g = 0; g < 3; ++g)
                    gi[g] = __builtin_amdgcn_mfma_f32_16x16x32_bf16(Eih[g], b, gi[g], 0, 0, 0);
            }
            f32x4 gh[3] = {erz4, ezz4, egn4};
            gemmB(sin_buf + m*136 + quad*8, Ehh, gh);
            f32x4 K;
            gateK(gi, gh, y, K);
            #pragma unroll
            for (int r = 0; r < 4; ++r) y[r] += K[r];
            st4(sout_buf + m*136 + hq, y);
            if (tid < 192) { bout_buf[eb*40 + ek] = f2bf(encv); encv = evn; }
            __syncthreads();
        }
    }
    // y(0) is in regs and in yTa (t=63 wrote yTa)

    // ---- persistent RK4 A-frags (loaded after encoder to limit pressure) ----
    short8 Ahh[3][4], Aih[3][4];
    #pragma unroll
    for (int g = 0; g < 3; ++g)
        #pragma unroll
        for (int c = 0; c < 4; ++c) {
            const float* ph = Wc_hh + (size_t)(g*NH + w*16 + m)*NH + c*32 + quad*8;
            const float* pi = Wc_ih + (size_t)(g*NH + w*16 + m)*NH + c*32 + quad*8;
            short8 fh, fi;
            #pragma unroll
            for (int j = 0; j < 8; ++j) { fh[j] = f2bf(scg[g]*ph[j]); fi[j] = f2bf(scg[g]*pi[j]); }
            Ahh[g][c] = fh; Aih[g][c] = fi;
        }
    short8 Aexp;
    #pragma unroll
    for (int j = 0; j < 8; ++j) {
        int k = quad*8 + j;
        Aexp[j] = (k < NKIN) ? f2bf(2.0f*LOG2E*W_e[(w*16 + m)*NKIN + k]) : (short)0;
    }
    short8 A1f[2][4];                              // head W1 frags, persistent
    #pragma unroll
    for (int kc = 0; kc < 4; ++kc) {
        A1f[0][kc] = *(const short8*)(w1f + (size_t)(((w    )*4 + kc)*64 + lane)*8);
        A1f[1][kc] = *(const short8*)(w1f + (size_t)(((w + 8)*4 + kc)*64 + lane)*8);
    }
    f32x4 brz4, bzz4, bgn4, bin4, be4;
    #pragma unroll
    for (int r = 0; r < 4; ++r) {
        int h = hq + r;
        brz4[r] = -LOG2E*(bc_ih[h]      + bc_hh[h]);
        bzz4[r] = -LOG2E*(bc_ih[NH + h] + bc_hh[NH + h]);
        bgn4[r] = 2.0f*LOG2E*bc_hh[2*NH + h];
        bin4[r] = 2.0f*LOG2E*bc_ih[2*NH + h];
        be4[r]  = 2.0f*LOG2E*b_e[h];
    }

    // ================= RK4 prologue =================
    const int sb = tid >> 3, sk = tid & 7;
    const size_t scol = (size_t)(b0 + sb)*NKIN + sk;
    // zero encoder-used cols 8..11 of both staging buffers
    if (tid < 128) {
        short* bb = (tid & 64) ? U1b : UMb;
        int rr = (tid >> 2) & 15, cc = 8 + (tid & 3);
        bb[rr*40 + cc] = 0;
    }
    if (tid < 128) UMb[sb*40 + sk] = f2bf(pre_x[(size_t)(NTP-1)*BKIN + scol]);
    __syncthreads();
    {   // x0 = tanh-expand(u0_start)
        short8 b = *(const short8*)(UMb + m*40 + quad*8);
        f32x4 c0 = be4;
        c0 = __builtin_amdgcn_mfma_f32_16x16x32_bf16(Aexp, b, c0, 0, 0, 0);
        f32x4 xv;
        #pragma unroll
        for (int r = 0; r < 4; ++r) xv[r] = tanh2(c0[r]);
        st4(xmT + m*136 + hq, xv);
    }
    __syncthreads();
    f32x4 gi0[3] = {z4, z4, bin4};
    gemmB(xmT + m*136 + quad*8, Aih, gi0);
    if (tid < 128) { UMb[sb*40 + sk] = f2bf(UM[scol]); U1b[sb*40 + sk] = f2bf(fx[scol]); }
    __syncthreads();
    {   // expand u(0)
        short8 bm = *(const short8*)(UMb + m*40 + quad*8);
        short8 b1 = *(const short8*)(U1b + m*40 + quad*8);
        f32x4 cm = be4, c1 = be4;
        cm = __builtin_amdgcn_mfma_f32_16x16x32_bf16(Aexp, bm, cm, 0, 0, 0);
        c1 = __builtin_amdgcn_mfma_f32_16x16x32_bf16(Aexp, b1, c1, 0, 0, 0);
        f32x4 xm, x1;
        #pragma unroll
        for (int r = 0; r < 4; ++r) { xm[r] = tanh2(cm[r]); x1[r] = tanh2(c1[r]); }
        st4(xmT + m*136 + hq, xm);
        st4(x1T + m*136 + hq, x1);
    }
    __syncthreads();
    f32x4 gim[3] = {z4, z4, bin4}, gi1[3] = {z4, z4, bin4};
    gemmB(xmT + m*136 + quad*8, Aih, gim);
    gemmB(x1T + m*136 + quad*8, Aih, gi1);
    float fxv = 0.f, umv = 0.f;
    if (tid < 128) { fxv = fx[(size_t)BKIN + scol]; umv = UM[(size_t)BKIN + scol]; }  // u(1)

    // ================= RK4 main loop: 4 barriers/step =================
    for (int st = 0; st < NL; ++st) {
        // ---- W1: k1 + head1(st-1) ----
        f32x4 gh[3] = {brz4, bzz4, bgn4};
        gemmB(yTa + m*136 + quad*8, Ahh, gh);
        if (st > 0) {
            f32x4 o0 = z4, o1 = z4;
            #pragma unroll
            for (int kc = 0; kc < 4; ++kc) {
                short8 b = *(const short8*)(yTa + m*136 + quad*8 + kc*32);
                o0 = __builtin_amdgcn_mfma_f32_16x16x32_bf16(A1f[0][kc], b, o0, 0, 0, 0);
                o1 = __builtin_amdgcn_mfma_f32_16x16x32_bf16(A1f[1][kc], b, o1, 0, 0, 0);
            }
            f32x4 t0, t1;
            #pragma unroll
            for (int r = 0; r < 4; ++r) { t0[r] = tanh2(o0[r]); t1[r] = tanh2(o1[r]); }
            st4(oT + m*264 + w*16     + quad*4, t0);
            st4(oT + m*264 + (w+8)*16 + quad*4, t1);
        }
        f32x4 K, Ks, ye;
        gateK(gi0, gh, y, K);
        #pragma unroll
        for (int r = 0; r < 4; ++r) { Ks[r] = K[r]; ye[r] = y[r] + 0.5f*K[r]; }
        st4(yTb + m*136 + hq, ye);
        __syncthreads();                                        // B1
        // ---- W2: k2 + stage2(st-1) + staging u(st+1) + prefetches ----
        float fxn = 0.f, umn = 0.f;
        if (tid < 128) {                                        // prefetch u(st+2) first
            int sn = (st + 2 < NL) ? st + 2 : NL - 1;
            fxn = fx[(size_t)sn*BKIN + scol];
            umn = UM[(size_t)sn*BKIN + scol];
        }
        if (st > 0 && w == ((st-1) & 7)) {
            short8 a2f[8];
            #pragma unroll
            for (int kc = 0; kc < 8; ++kc)
                a2f[kc] = *(const short8*)(w2f + (size_t)(kc*64 + lane)*8);
            f32x4 oc = z4;
            #pragma unroll
            for (int kc = 0; kc < 8; ++kc) {
                short8 b = *(const short8*)(oT + m*264 + kc*32 + quad*8);
                oc = __builtin_amdgcn_mfma_f32_16x16x32_bf16(a2f[kc], b, oc, 0, 0, 0);
            }
            if (quad == 0)
                *(f32x4*)(out + ((size_t)(st-1)*NB + b0 + m)*NKOUT) = oc;
        }
        if (tid < 128) { UMb[sb*40 + sk] = f2bf(umv); U1b[sb*40 + sk] = f2bf(fxv); }
        gh[0] = brz4; gh[1] = bzz4; gh[2] = bgn4;
        gemmB(yTb + m*136 + quad*8, Ahh, gh);
        gateK(gim, gh, ye, K);
        #pragma unroll
        for (int r = 0; r < 4; ++r) { Ks[r] += 2.f*K[r]; ye[r] = y[r] + 0.5f*K[r]; }
        st4(E1 + m*136 + hq, ye);
        fxv = fxn; umv = umn;
        __syncthreads();                                        // B2
        // ---- W3: k3 + expand(st+1) ----
        gh[0] = brz4; gh[1] = bzz4; gh[2] = bgn4;
        gemmB(E1 + m*136 + quad*8, Ahh, gh);
        {
            short8 bm = *(const short8*)(UMb + m*40 + quad*8);
            short8 b1 = *(const short8*)(U1b + m*40 + quad*8);
            f32x4 cm = be4, c1 = be4;
            cm = __builtin_amdgcn_mfma_f32_16x16x32_bf16(Aexp, bm, cm, 0, 0, 0);
            c1 = __builtin_amdgcn_mfma_f32_16x16x32_bf16(Aexp, b1, c1, 0, 0, 0);
            f32x4 xm, x1;
            #pragma unroll
            for (int r = 0; r < 4; ++r) { xm[r] = tanh2(cm[r]); x1[r] = tanh2(c1[r]); }
            st4(xmT + m*136 + hq, xm);
            st4(x1T + m*136 + hq, x1);
        }
        gateK(gim, gh, ye, K);
        #pragma unroll
        for (int r = 0; r < 4; ++r) { Ks[r] += 2.f*K[r]; ye[r] = y[r] + K[r]; }
        st4(yTb + m*136 + hq, ye);
        __syncthreads();                                        // B3
        // ---- W4: k4 + y update + gim/gi1(st+1) ----
        gh[0] = brz4; gh[1] = bzz4; gh[2] = bgn4;
        gemmB(yTb + m*136 + quad*8, Ahh, gh);
        gateK(gi1, gh, ye, K);
        #pragma unroll
        for (int r = 0; r < 4; ++r) y[r] += (1.0f/6.0f)*(Ks[r] + K[r]);
        st4(yTa + m*136 + hq, y);
        gi0[0] = gi1[0]; gi0[1] = gi1[1]; gi0[2] = gi1[2];
        gim[0] = z4; gim[1] = z4; gim[2] = bin4;
        gi1[0] = z4; gi1[1] = z4; gi1[2] = bin4;
        gemmB(xmT + m*136 + quad*8, Aih, gim);
        gemmB(x1T + m*136 + quad*8, Aih, gi1);
        __syncthreads();                                        // B4
    }

    // ================= epilogue: head(127) =================
    {
        f32x4 o0 = z4, o1 = z4;
        #pragma unroll
        for (int kc = 0; kc < 4; ++kc) {
            short8 b = *(const short8*)(yTa + m*136 + quad*8 + kc*32);
            o0 = __builtin_amdgcn_mfma_f32_16x16x32_bf16(A1f[0][kc], b, o0, 0, 0, 0);
            o1 = __builtin_amdgcn_mfma_f32_16x16x32_bf16(A1f[1][kc], b, o1, 0, 0, 0);
        }
        f32x4 t0, t1;
        #pragma unroll
        for (int r = 0; r < 4; ++r) { t0[r] = tanh2(o0[r]); t1[r] = tanh2(o1[r]); }
        st4(oT + m*264 + w*16     + quad*4, t0);
        st4(oT + m*264 + (w+8)*16 + quad*4, t1);
        short8 a2f[8];
        if (w == 7) {
            #pragma unroll
            for (int kc = 0; kc < 8; ++kc)
                a2f[kc] = *(const short8*)(w2f + (size_t)(kc*64 + lane)*8);
        }
        __syncthreads();
        if (w == 7) {
            f32x4 oc = z4;
            #pragma unroll
            for (int kc = 0; kc < 8; ++kc) {
                short8 b = *(const short8*)(oT + m*264 + kc*32 + quad*8);
                oc = __builtin_amdgcn_mfma_f32_16x16x32_bf16(a2f[kc], b, oc, 0, 0, 0);
            }
            if (quad == 0)
                *(f32x4*)(out + ((size_t)(NL-1)*NB + b0 + m)*NKOUT) = oc;
        }
    }
}

extern "C" void kernel_launch(void* const* d_in, const int* in_sizes, int n_in,
                              void* d_out, int out_size, void* d_ws, size_t ws_size,
                              hipStream_t stream)
{
    const float* pre_x = (const float*)d_in[0];
    const float* pre_y = (const float*)d_in[1];
    const float* fx    = (const float*)d_in[2];
    const float* W_ih  = (const float*)d_in[3];
    const float* W_hh  = (const float*)d_in[4];
    const float* b_ih  = (const float*)d_in[5];
    const float* b_hh  = (const float*)d_in[6];
    const float* W_e   = (const float*)d_in[7];
    const float* b_e   = (const float*)d_in[8];
    const float* Wc_ih = (const float*)d_in[9];
    const float* Wc_hh = (const float*)d_in[10];
    const float* bc_ih = (const float*)d_in[11];
    const float* bc_hh = (const float*)d_in[12];
    const float* W1    = (const float*)d_in[13];
    const float* W2    = (const float*)d_in[14];
    float* out = (float*)d_out;

    float* UM  = (float*)d_ws;                                  // 128*4096*8 fp32 = 16.78 MB
    short* w1f = (short*)((char*)d_ws + (size_t)NL*NB*NKIN*4);  // 32768 shorts
    short* w2f = w1f + 16*4*64*8;                               // 4096 shorts

    prep_frags<<<dim3(1), dim3(256), 0, stream>>>(W1, W2, w1f, w2f);
    spline_um_kernel<<<dim3((NB*NKIN)/128), dim3(128), 0, stream>>>(pre_x, fx, UM);
    fused_kernel<<<dim3(NB/16), dim3(512), 0, stream>>>(
        pre_x, pre_y, fx, W_ih, W_hh, b_ih, b_hh, W_e, b_e,
        Wc_ih, Wc_hh, bc_ih, bc_hh, UM, w1f, w2f, out);
}

// Round 5
// 840.356 us; speedup vs baseline: 1.0034x; 1.0034x over previous
//
#include <hip/hip_runtime.h>
#include <math.h>

#define NB    4096
#define NH    128
#define NKIN  8
#define NKOUT 4
#define NTP   64
#define NL    128
#define BKIN  (NB*NKIN)
#define LOG2E 1.44269504088896340736f

typedef __attribute__((ext_vector_type(8))) short short8;
typedef __attribute__((ext_vector_type(4))) float f32x4;

#if __has_builtin(__builtin_amdgcn_exp2f)
#define EXP2F __builtin_amdgcn_exp2f
#else
#define EXP2F exp2f
#endif

__device__ __forceinline__ short f2bf(float f) {
    union { float f; unsigned u; } v; v.f = f;
    unsigned u = v.u;
    return (short)((u + 0x7fffu + ((u >> 16) & 1u)) >> 16);
}
__device__ __forceinline__ unsigned pkbf2(float a, float b) {
#if __has_builtin(__builtin_amdgcn_cvt_pk_bf16_f32)
    auto p = __builtin_amdgcn_cvt_pk_bf16_f32(a, b);
    unsigned q; __builtin_memcpy(&q, &p, 4); return q;
#else
    union { float f; unsigned u; } x, y; x.f = a; y.f = b;
    unsigned ua = (x.u + 0x7fffu + ((x.u >> 16) & 1u)) >> 16;
    unsigned ub = (y.u + 0x7fffu + ((y.u >> 16) & 1u)) & 0xffff0000u;
    return ua | ub;
#endif
}
__device__ __forceinline__ void st4(short* dst, const f32x4& v) {
    uint2 q; q.x = pkbf2(v[0], v[1]); q.y = pkbf2(v[2], v[3]);
    *(uint2*)dst = q;
}
__device__ __forceinline__ f32x4 exp24(f32x4 a) {
    f32x4 r;
    #pragma unroll
    for (int i = 0; i < 4; ++i) r[i] = EXP2F(a[i]);
    return r;
}
__device__ __forceinline__ f32x4 rcp4(f32x4 a) {
    f32x4 r;
    #pragma unroll
    for (int i = 0; i < 4; ++i) r[i] = __builtin_amdgcn_rcpf(a[i]);
    return r;
}

// ---------------- spline: Thomas solve -> UM (midpoint control values) ----
__global__ void spline_um_kernel(const float* __restrict__ pre_x,
                                 const float* __restrict__ fx,
                                 float* __restrict__ UM)
{
    __shared__ float cp[128];
    if (threadIdx.x == 0) {
        float c = 0.f;
        for (int j = 1; j <= 127; ++j) { c = 1.0f/(4.0f - c); cp[j] = c; }
    }
    __syncthreads();
    int col = blockIdx.x*128 + threadIdx.x;
    const float r6 = 6.0f/(0.1f*0.1f);
    const float KK = 0.01f/16.0f;   // hs^2/16
    float y0 = pre_x[(size_t)(NTP-1)*BKIN + col];
    float y1 = fx[col];
    float d = 0.f;
    for (int j = 1; j <= 127; ++j) {
        float y2 = fx[(size_t)j*BKIN + col];
        float r  = r6*(y0 - 2.f*y1 + y2);
        d = (r - d)*cp[j];
        UM[(size_t)j*BKIN + col] = d;
        y0 = y1; y1 = y2;
    }
    float xn  = 0.f;
    float yj1 = fx[(size_t)127*BKIN + col];
    for (int j = 127; j >= 1; --j) {
        float dj = UM[(size_t)j*BKIN + col];
        float x  = dj - cp[j]*xn;                    // M_j
        float yj = fx[(size_t)(j-1)*BKIN + col];
        UM[(size_t)j*BKIN + col] = 0.5f*(yj + yj1) - KK*(x + xn);
        xn = x; yj1 = yj;
    }
    float ys0 = pre_x[(size_t)(NTP-1)*BKIN + col];
    UM[col] = 0.5f*(ys0 + yj1) - KK*xn;
}

// ---------------- prep: W1/W2 as A-operand fragments (bf16, W1 pre-scaled) ----
__global__ void prep_frags(const float* __restrict__ W1, const float* __restrict__ W2,
                           short* __restrict__ w1f, short* __restrict__ w2f)
{
    int tid = threadIdx.x;
    for (int idx = tid; idx < 16*4*64*8; idx += 256) {
        int j = idx & 7, lane = (idx >> 3) & 63, kc = (idx >> 9) & 3, t = idx >> 11;
        int row = t*16 + (lane & 15);
        int k   = kc*32 + (lane >> 4)*8 + j;
        w1f[idx] = f2bf(2.0f*LOG2E*W1[row*NH + k]);
    }
    for (int idx = tid; idx < 8*64*8; idx += 256) {
        int j = idx & 7, lane = (idx >> 3) & 63, kc = idx >> 9;
        int m = lane & 15;
        int k = kc*32 + (lane >> 4)*8 + j;
        w2f[idx] = (m < NKOUT) ? f2bf(W2[m*2*NH + k]) : (short)0;
    }
}

// ---------------- fused kernel helpers ----------------
__device__ __forceinline__ void ld4(const short* bp, short8 (&bf)[4]) {
    #pragma unroll
    for (int kc = 0; kc < 4; ++kc) bf[kc] = *(const short8*)(bp + kc*32);
}
__device__ __forceinline__ void gemmR(const short8 (&bf)[4], const short8 (&A)[3][4],
                                      f32x4 (&acc)[3]) {
    #pragma unroll
    for (int kc = 0; kc < 4; ++kc)
        #pragma unroll
        for (int g = 0; g < 3; ++g)
            acc[g] = __builtin_amdgcn_mfma_f32_16x16x32_bf16(A[g][kc], bf[kc], acc[g], 0, 0, 0);
}
__device__ __forceinline__ void gemmB(const short* bp, const short8 (&A)[3][4], f32x4 (&acc)[3]) {
    short8 bf[4]; ld4(bp, bf); gemmR(bf, A, acc);
}
// r-gate scaled -LOG2E (rg = sigmoid), z-gate scaled +LOG2E (zc = 1-z),
// n-gate scaled 2*LOG2E (tanh). K = (1-z)*(n - y).
__device__ __forceinline__ void gateK(const f32x4 (&gi)[3], const f32x4 (&gh)[3],
                                      const f32x4& yin, f32x4& K)
{
    f32x4 rg = rcp4(exp24(gi[0] + gh[0]) + 1.0f);
    f32x4 zc = rcp4(exp24(gi[1] + gh[1]) + 1.0f);
    f32x4 tg = 1.0f - 2.0f*rcp4(exp24(gi[2] + rg*gh[2]) + 1.0f);
    K = zc*(tg - yin);
}

__global__ void __launch_bounds__(512, 2)
fused_kernel(const float* __restrict__ pre_x, const float* __restrict__ pre_y,
             const float* __restrict__ fx,
             const float* __restrict__ W_ih, const float* __restrict__ W_hh,
             const float* __restrict__ b_ih, const float* __restrict__ b_hh,
             const float* __restrict__ W_e,  const float* __restrict__ b_e,
             const float* __restrict__ Wc_ih,const float* __restrict__ Wc_hh,
             const float* __restrict__ bc_ih,const float* __restrict__ bc_hh,
             const float* __restrict__ UM,   const short* __restrict__ w1f,
             const short* __restrict__ w2f,  float* __restrict__ out)
{
    __shared__ __align__(16) short yTa[16*136];   // enc ping / RK4 y
    __shared__ __align__(16) short yTb[16*136];   // enc pong / RK4 ye1, ye3
    __shared__ __align__(16) short E1 [16*136];   // ye2
    __shared__ __align__(16) short xmT[16*136];
    __shared__ __align__(16) short x1T[16*136];
    __shared__ __align__(16) short UMb[16*40];
    __shared__ __align__(16) short U1b[16*40];
    __shared__ __align__(16) short oT [16*264];

    const int tid  = threadIdx.x;
    const int w    = tid >> 6;
    const int lane = tid & 63;
    const int quad = lane >> 4;
    const int m    = lane & 15;
    const int hq   = w*16 + quad*4;
    const int b0   = blockIdx.x * 16;
    const f32x4 z4 = {0.f, 0.f, 0.f, 0.f};
    const float scg[3] = {-LOG2E, LOG2E, 2.0f*LOG2E};   // r, z(flipped), n

    for (int i = tid; i < 16*136; i += 512) yTa[i] = 0;
    for (int i = tid; i < 16*40;  i += 512) { UMb[i] = 0; U1b[i] = 0; }

    f32x4 y = z4;

    // ================= encoder GRU: 1 barrier/step, spread staging =================
    {
        short8 Ehh[3][4];
        #pragma unroll
        for (int g = 0; g < 3; ++g)
            #pragma unroll
            for (int c = 0; c < 4; ++c) {
                const float* ph = W_hh + (size_t)(g*NH + w*16 + m)*NH + c*32 + quad*8;
                short8 fh;
                #pragma unroll
                for (int j = 0; j < 8; ++j) fh[j] = f2bf(scg[g]*ph[j]);
                Ehh[g][c] = fh;
            }
        short8 Eih[3];
        #pragma unroll
        for (int g = 0; g < 3; ++g) {
            short8 f1;
            #pragma unroll
            for (int j = 0; j < 8; ++j) {
                int k = quad*8 + j;
                f1[j] = (k < 12) ? f2bf(scg[g]*W_ih[(size_t)(g*NH + w*16 + m)*12 + k]) : (short)0;
            }
            Eih[g] = f1;
        }
        f32x4 erz4, ezz4, egn4, ein4;
        #pragma unroll
        for (int r = 0; r < 4; ++r) {
            int h = hq + r;
            erz4[r] = -LOG2E*(b_ih[h]      + b_hh[h]);
            ezz4[r] =  LOG2E*(b_ih[NH + h] + b_hh[NH + h]);
            egn4[r] = 2.0f*LOG2E*b_hh[2*NH + h];
            ein4[r] = 2.0f*LOG2E*b_ih[2*NH + h];
        }
        // spread staging: 192 elements over 8 waves x 24 lanes
        const int eidx = w*24 + lane;
        const int eb = eidx/12, ek = eidx - 12*eb;
        const bool estg = (lane < 24);
        float encv = 0.f;
        if (estg) {
            float e0 = (ek < NKIN) ? pre_x[((size_t)0*NB + b0 + eb)*NKIN + ek]
                                   : pre_y[((size_t)0*NB + b0 + eb)*NKOUT + (ek - NKIN)];
            UMb[eb*40 + ek] = f2bf(e0);
            encv = (ek < NKIN) ? pre_x[((size_t)1*NB + b0 + eb)*NKIN + ek]
                               : pre_y[((size_t)1*NB + b0 + eb)*NKOUT + (ek - NKIN)];
        }
        __syncthreads();
        for (int t = 0; t < NTP; ++t) {
            float evn = 0.f;
            if (estg) {
                int tn = (t + 2 < NTP) ? t + 2 : NTP - 1;
                evn = (ek < NKIN) ? pre_x[((size_t)tn*NB + b0 + eb)*NKIN + ek]
                                  : pre_y[((size_t)tn*NB + b0 + eb)*NKOUT + (ek - NKIN)];
            }
            const short* bin_buf  = (t & 1) ? U1b : UMb;
            short*       bout_buf = (t & 1) ? UMb : U1b;
            const short* sin_buf  = (t & 1) ? yTb : yTa;
            short*       sout_buf = (t & 1) ? yTa : yTb;
            f32x4 gi[3] = {z4, z4, ein4};
            {
                short8 b = *(const short8*)(bin_buf + m*40 + quad*8);
                #pragma unroll
                for (int g = 0; g < 3; ++g)
                    gi[g] = __builtin_amdgcn_mfma_f32_16x16x32_bf16(Eih[g], b, gi[g], 0, 0, 0);
            }
            f32x4 gh[3] = {erz4, ezz4, egn4};
            gemmB(sin_buf + m*136 + quad*8, Ehh, gh);
            f32x4 K;
            gateK(gi, gh, y, K);
            y += K;
            st4(sout_buf + m*136 + hq, y);
            if (estg) { bout_buf[eb*40 + ek] = f2bf(encv); encv = evn; }
            __syncthreads();
        }
    }

    // ---- persistent RK4 A-frags ----
    short8 Ahh[3][4], Aih[3][4];
    #pragma unroll
    for (int g = 0; g < 3; ++g)
        #pragma unroll
        for (int c = 0; c < 4; ++c) {
            const float* ph = Wc_hh + (size_t)(g*NH + w*16 + m)*NH + c*32 + quad*8;
            const float* pi = Wc_ih + (size_t)(g*NH + w*16 + m)*NH + c*32 + quad*8;
            short8 fh, fi;
            #pragma unroll
            for (int j = 0; j < 8; ++j) { fh[j] = f2bf(scg[g]*ph[j]); fi[j] = f2bf(scg[g]*pi[j]); }
            Ahh[g][c] = fh; Aih[g][c] = fi;
        }
    short8 Aexp;
    #pragma unroll
    for (int j = 0; j < 8; ++j) {
        int k = quad*8 + j;
        Aexp[j] = (k < NKIN) ? f2bf(2.0f*LOG2E*W_e[(w*16 + m)*NKIN + k]) : (short)0;
    }
    short8 A1f[2][4];
    #pragma unroll
    for (int kc = 0; kc < 4; ++kc) {
        A1f[0][kc] = *(const short8*)(w1f + (size_t)(((w    )*4 + kc)*64 + lane)*8);
        A1f[1][kc] = *(const short8*)(w1f + (size_t)(((w + 8)*4 + kc)*64 + lane)*8);
    }
    f32x4 brz4, bzz4, bgn4, bin4, be4;
    #pragma unroll
    for (int r = 0; r < 4; ++r) {
        int h = hq + r;
        brz4[r] = -LOG2E*(bc_ih[h]      + bc_hh[h]);
        bzz4[r] =  LOG2E*(bc_ih[NH + h] + bc_hh[NH + h]);
        bgn4[r] = 2.0f*LOG2E*bc_hh[2*NH + h];
        bin4[r] = 2.0f*LOG2E*bc_ih[2*NH + h];
        be4[r]  = 2.0f*LOG2E*b_e[h];
    }

    // ================= RK4 prologue =================
    // spread staging: 128 elements over 8 waves x 16 lanes (2 batches/wave)
    const bool stg = (lane < 16);
    const int sb = w*2 + (lane >> 3), sk = lane & 7;
    const size_t scol = (size_t)(b0 + sb)*NKIN + sk;
    if (stg) {   // zero enc cols 8..11 (dup writes ok) + stage u0_start
        UMb[sb*40 + 8 + (lane & 3)] = 0;
        U1b[sb*40 + 8 + (lane & 3)] = 0;
        UMb[sb*40 + sk] = f2bf(pre_x[(size_t)(NTP-1)*BKIN + scol]);
    }
    __syncthreads();
    {   // x0 = tanh-expand(u0_start) -> xmT
        short8 b = *(const short8*)(UMb + m*40 + quad*8);
        f32x4 c0 = be4;
        c0 = __builtin_amdgcn_mfma_f32_16x16x32_bf16(Aexp, b, c0, 0, 0, 0);
        f32x4 xv = 1.0f - 2.0f*rcp4(exp24(c0) + 1.0f);
        st4(xmT + m*136 + hq, xv);
    }
    __syncthreads();
    f32x4 gi0[3] = {z4, z4, bin4};
    gemmB(xmT + m*136 + quad*8, Aih, gi0);
    if (stg) { UMb[sb*40 + sk] = f2bf(UM[scol]); U1b[sb*40 + sk] = f2bf(fx[scol]); }
    __syncthreads();
    {   // expand u(0) -> xmT, x1T
        short8 bm = *(const short8*)(UMb + m*40 + quad*8);
        short8 b1 = *(const short8*)(U1b + m*40 + quad*8);
        f32x4 cm = be4, c1 = be4;
        cm = __builtin_amdgcn_mfma_f32_16x16x32_bf16(Aexp, bm, cm, 0, 0, 0);
        c1 = __builtin_amdgcn_mfma_f32_16x16x32_bf16(Aexp, b1, c1, 0, 0, 0);
        f32x4 xm = 1.0f - 2.0f*rcp4(exp24(cm) + 1.0f);
        f32x4 x1 = 1.0f - 2.0f*rcp4(exp24(c1) + 1.0f);
        st4(xmT + m*136 + hq, xm);
        st4(x1T + m*136 + hq, x1);
    }
    float fxv = 0.f, umv = 0.f;
    if (stg) { fxv = fx[(size_t)BKIN + scol]; umv = UM[(size_t)BKIN + scol]; }  // u(1)
    __syncthreads();

    // ================= RK4 loop: 4 balanced phases/step =================
    for (int st = 0; st < NL; ++st) {
        // ---- W1: k1 + gim(st) ----
        short8 byf[4];
        ld4(yTa + m*136 + quad*8, byf);               // reused by head1 in W2
        f32x4 gh[3] = {brz4, bzz4, bgn4};
        gemmR(byf, Ahh, gh);
        f32x4 gim[3] = {z4, z4, bin4};
        gemmB(xmT + m*136 + quad*8, Aih, gim);        // independent: hides gate latency
        f32x4 K, Ks, ye;
        gateK(gi0, gh, y, K);
        Ks = K; ye = y + 0.5f*K;
        st4(yTb + m*136 + hq, ye);
        __syncthreads();                                        // B1
        // ---- W2: k2 + head1(st-1) + staging u(st+1) ----
        if (stg) { UMb[sb*40 + sk] = f2bf(umv); U1b[sb*40 + sk] = f2bf(fxv); }
        gh[0] = brz4; gh[1] = bzz4; gh[2] = bgn4;
        gemmB(yTb + m*136 + quad*8, Ahh, gh);
        if (st > 0) {
            f32x4 o0 = z4, o1 = z4;
            #pragma unroll
            for (int kc = 0; kc < 4; ++kc) {
                o0 = __builtin_amdgcn_mfma_f32_16x16x32_bf16(A1f[0][kc], byf[kc], o0, 0, 0, 0);
                o1 = __builtin_amdgcn_mfma_f32_16x16x32_bf16(A1f[1][kc], byf[kc], o1, 0, 0, 0);
            }
            f32x4 t0 = 1.0f - 2.0f*rcp4(exp24(o0) + 1.0f);
            f32x4 t1 = 1.0f - 2.0f*rcp4(exp24(o1) + 1.0f);
            st4(oT + m*264 + w*16     + quad*4, t0);
            st4(oT + m*264 + (w+8)*16 + quad*4, t1);
        }
        gateK(gim, gh, ye, K);
        Ks += 2.0f*K; ye = y + 0.5f*K;
        st4(E1 + m*136 + hq, ye);
        __syncthreads();                                        // B2
        // ---- W3: k3 + gi1(st) + prefetch u(st+2) ----
        if (stg) {
            int sn = (st + 2 < NL) ? st + 2 : NL - 1;
            fxv = fx[(size_t)sn*BKIN + scol];
            umv = UM[(size_t)sn*BKIN + scol];
        }
        gh[0] = brz4; gh[1] = bzz4; gh[2] = bgn4;
        gemmB(E1 + m*136 + quad*8, Ahh, gh);
        f32x4 gi1[3] = {z4, z4, bin4};
        gemmB(x1T + m*136 + quad*8, Aih, gi1);
        gateK(gim, gh, ye, K);
        Ks += 2.0f*K; ye = y + K;
        st4(yTb + m*136 + hq, ye);
        __syncthreads();                                        // B3
        // ---- W4: k4 + expand(st+1) + stage2(st-1) ----
        short8 a2f[8];
        const bool s2w = (st > 0) && (w == ((st-1) & 7));
        if (s2w) {
            #pragma unroll
            for (int kc = 0; kc < 8; ++kc)
                a2f[kc] = *(const short8*)(w2f + (size_t)(kc*64 + lane)*8);
        }
        gh[0] = brz4; gh[1] = bzz4; gh[2] = bgn4;
        gemmB(yTb + m*136 + quad*8, Ahh, gh);
        {   // expand u(st+1)
            short8 bm = *(const short8*)(UMb + m*40 + quad*8);
            short8 b1 = *(const short8*)(U1b + m*40 + quad*8);
            f32x4 cm = be4, c1 = be4;
            cm = __builtin_amdgcn_mfma_f32_16x16x32_bf16(Aexp, bm, cm, 0, 0, 0);
            c1 = __builtin_amdgcn_mfma_f32_16x16x32_bf16(Aexp, b1, c1, 0, 0, 0);
            f32x4 xm = 1.0f - 2.0f*rcp4(exp24(cm) + 1.0f);
            f32x4 x1 = 1.0f - 2.0f*rcp4(exp24(c1) + 1.0f);
            st4(xmT + m*136 + hq, xm);
            st4(x1T + m*136 + hq, x1);
        }
        if (s2w) {
            f32x4 oc = z4;
            #pragma unroll
            for (int kc = 0; kc < 8; ++kc) {
                short8 b = *(const short8*)(oT + m*264 + kc*32 + quad*8);
                oc = __builtin_amdgcn_mfma_f32_16x16x32_bf16(a2f[kc], b, oc, 0, 0, 0);
            }
            if (quad == 0)
                *(f32x4*)(out + ((size_t)(st-1)*NB + b0 + m)*NKOUT) = oc;
        }
        gateK(gi1, gh, ye, K);
        y += (1.0f/6.0f)*(Ks + K);
        st4(yTa + m*136 + hq, y);
        gi0[0] = gi1[0]; gi0[1] = gi1[1]; gi0[2] = gi1[2];
        __syncthreads();                                        // B4
    }

    // ================= epilogue: head(127) =================
    {
        short8 byf[4];
        ld4(yTa + m*136 + quad*8, byf);
        f32x4 o0 = z4, o1 = z4;
        #pragma unroll
        for (int kc = 0; kc < 4; ++kc) {
            o0 = __builtin_amdgcn_mfma_f32_16x16x32_bf16(A1f[0][kc], byf[kc], o0, 0, 0, 0);
            o1 = __builtin_amdgcn_mfma_f32_16x16x32_bf16(A1f[1][kc], byf[kc], o1, 0, 0, 0);
        }
        f32x4 t0 = 1.0f - 2.0f*rcp4(exp24(o0) + 1.0f);
        f32x4 t1 = 1.0f - 2.0f*rcp4(exp24(o1) + 1.0f);
        st4(oT + m*264 + w*16     + quad*4, t0);
        st4(oT + m*264 + (w+8)*16 + quad*4, t1);
        short8 a2f[8];
        if (w == 7) {
            #pragma unroll
            for (int kc = 0; kc < 8; ++kc)
                a2f[kc] = *(const short8*)(w2f + (size_t)(kc*64 + lane)*8);
        }
        __syncthreads();
        if (w == 7) {
            f32x4 oc = z4;
            #pragma unroll
            for (int kc = 0; kc < 8; ++kc) {
                short8 b = *(const short8*)(oT + m*264 + kc*32 + quad*8);
                oc = __builtin_amdgcn_mfma_f32_16x16x32_bf16(a2f[kc], b, oc, 0, 0, 0);
            }
            if (quad == 0)
                *(f32x4*)(out + ((size_t)(NL-1)*NB + b0 + m)*NKOUT) = oc;
        }
    }
}

extern "C" void kernel_launch(void* const* d_in, const int* in_sizes, int n_in,
                              void* d_out, int out_size, void* d_ws, size_t ws_size,
                              hipStream_t stream)
{
    const float* pre_x = (const float*)d_in[0];
    const float* pre_y = (const float*)d_in[1];
    const float* fx    = (const float*)d_in[2];
    const float* W_ih  = (const float*)d_in[3];
    const float* W_hh  = (const float*)d_in[4];
    const float* b_ih  = (const float*)d_in[5];
    const float* b_hh  = (const float*)d_in[6];
    const float* W_e   = (const float*)d_in[7];
    const float* b_e   = (const float*)d_in[8];
    const float* Wc_ih = (const float*)d_in[9];
    const float* Wc_hh = (const float*)d_in[10];
    const float* bc_ih = (const float*)d_in[11];
    const float* bc_hh = (const float*)d_in[12];
    const float* W1    = (const float*)d_in[13];
    const float* W2    = (const float*)d_in[14];
    float* out = (float*)d_out;

    float* UM  = (float*)d_ws;                                  // 128*4096*8 fp32 = 16.78 MB
    short* w1f = (short*)((char*)d_ws + (size_t)NL*NB*NKIN*4);  // 32768 shorts
    short* w2f = w1f + 16*4*64*8;                               // 4096 shorts

    prep_frags<<<dim3(1), dim3(256), 0, stream>>>(W1, W2, w1f, w2f);
    spline_um_kernel<<<dim3((NB*NKIN)/128), dim3(128), 0, stream>>>(pre_x, fx, UM);
    fused_kernel<<<dim3(NB/16), dim3(512), 0, stream>>>(
        pre_x, pre_y, fx, W_ih, W_hh, b_ih, b_hh, W_e, b_e,
        Wc_ih, Wc_hh, bc_ih, bc_hh, UM, w1f, w2f, out);
}

// Round 7
// 717.073 us; speedup vs baseline: 1.1759x; 1.1719x over previous
//
#include <hip/hip_runtime.h>
#include <math.h>

#define NB    4096
#define NH    128
#define NKIN  8
#define NKOUT 4
#define NTP   64
#define NL    128
#define BKIN  (NB*NKIN)
#define LOG2E 1.44269504088896340736f

typedef __attribute__((ext_vector_type(8))) short short8;
typedef __attribute__((ext_vector_type(4))) float f32x4;

#if __has_builtin(__builtin_amdgcn_exp2f)
#define EXP2F __builtin_amdgcn_exp2f
#else
#define EXP2F exp2f
#endif

__device__ __forceinline__ short f2bf(float f) {
    union { float f; unsigned u; } v; v.f = f;
    unsigned u = v.u;
    return (short)((u + 0x7fffu + ((u >> 16) & 1u)) >> 16);
}
__device__ __forceinline__ unsigned pkbf2(float a, float b) {
#if __has_builtin(__builtin_amdgcn_cvt_pk_bf16_f32)
    auto p = __builtin_amdgcn_cvt_pk_bf16_f32(a, b);
    unsigned q; __builtin_memcpy(&q, &p, 4); return q;
#else
    union { float f; unsigned u; } x, y; x.f = a; y.f = b;
    unsigned ua = (x.u + 0x7fffu + ((x.u >> 16) & 1u)) >> 16;
    unsigned ub = (y.u + 0x7fffu + ((y.u >> 16) & 1u)) & 0xffff0000u;
    return ua | ub;
#endif
}
__device__ __forceinline__ void st4(short* dst, const f32x4& v) {
    uint2 q; q.x = pkbf2(v[0], v[1]); q.y = pkbf2(v[2], v[3]);
    *(uint2*)dst = q;
}
__device__ __forceinline__ f32x4 exp24(f32x4 a) {
    f32x4 r;
    #pragma unroll
    for (int i = 0; i < 4; ++i) r[i] = EXP2F(a[i]);
    return r;
}
__device__ __forceinline__ f32x4 rcp4(f32x4 a) {
    f32x4 r;
    #pragma unroll
    for (int i = 0; i < 4; ++i) r[i] = __builtin_amdgcn_rcpf(a[i]);
    return r;
}

// ---------------- prep: W1/W2 as A-operand fragments (bf16, W1 pre-scaled) ----
__global__ void prep_frags(const float* __restrict__ W1, const float* __restrict__ W2,
                           short* __restrict__ w1f, short* __restrict__ w2f)
{
    int tid0 = blockIdx.x*256 + threadIdx.x;
    for (int idx = tid0; idx < 16*4*64*8; idx += 8*256) {
        int j = idx & 7, lane = (idx >> 3) & 63, kc = (idx >> 9) & 3, t = idx >> 11;
        int row = t*16 + (lane & 15);
        int k   = kc*32 + (lane >> 4)*8 + j;
        w1f[idx] = f2bf(2.0f*LOG2E*W1[row*NH + k]);
    }
    for (int idx = tid0; idx < 8*64*8; idx += 8*256) {
        int j = idx & 7, lane = (idx >> 3) & 63, kc = idx >> 9;
        int m = lane & 15;
        int k = kc*32 + (lane >> 4)*8 + j;
        w2f[idx] = (m < NKOUT) ? f2bf(W2[m*2*NH + k]) : (short)0;
    }
}

// ---------------- fused kernel helpers ----------------
__device__ __forceinline__ void ld4(const short* bp, short8 (&bf)[4]) {
    #pragma unroll
    for (int kc = 0; kc < 4; ++kc) bf[kc] = *(const short8*)(bp + kc*32);
}
__device__ __forceinline__ void gemmR(const short8 (&bf)[4], const short8 (&A)[3][4],
                                      f32x4 (&acc)[3]) {
    #pragma unroll
    for (int kc = 0; kc < 4; ++kc)
        #pragma unroll
        for (int g = 0; g < 3; ++g)
            acc[g] = __builtin_amdgcn_mfma_f32_16x16x32_bf16(A[g][kc], bf[kc], acc[g], 0, 0, 0);
}
__device__ __forceinline__ void gemmB(const short* bp, const short8 (&A)[3][4], f32x4 (&acc)[3]) {
    short8 bf[4]; ld4(bp, bf); gemmR(bf, A, acc);
}
// r-gate scaled -LOG2E (rg = sigmoid), z-gate scaled +LOG2E (zc = 1-z),
// n-gate scaled 2*LOG2E (tanh). K = (1-z)*(n - y).
__device__ __forceinline__ void gateK(const f32x4 (&gi)[3], const f32x4 (&gh)[3],
                                      const f32x4& yin, f32x4& K)
{
    f32x4 rg = rcp4(exp24(gi[0] + gh[0]) + 1.0f);
    f32x4 zc = rcp4(exp24(gi[1] + gh[1]) + 1.0f);
    f32x4 tg = 1.0f - 2.0f*rcp4(exp24(gi[2] + rg*gh[2]) + 1.0f);
    K = zc*(tg - yin);
}

__global__ void __launch_bounds__(512, 2)
fused_kernel(const float* __restrict__ pre_x, const float* __restrict__ pre_y,
             const float* __restrict__ fx,
             const float* __restrict__ W_ih, const float* __restrict__ W_hh,
             const float* __restrict__ b_ih, const float* __restrict__ b_hh,
             const float* __restrict__ W_e,  const float* __restrict__ b_e,
             const float* __restrict__ Wc_ih,const float* __restrict__ Wc_hh,
             const float* __restrict__ bc_ih,const float* __restrict__ bc_hh,
             float* __restrict__ UM,         const short* __restrict__ w1f,
             const short* __restrict__ w2f,  float* __restrict__ out)
{
    __shared__ __align__(16) short yTa[16*136];   // enc ping / RK4 y
    __shared__ __align__(16) short yTb[16*136];   // enc pong / RK4 ye1, ye3
    __shared__ __align__(16) short E1 [16*136];   // spline cp (prologue) / ye2
    __shared__ __align__(16) short xmT[16*136];
    __shared__ __align__(16) short x1T[16*136];
    __shared__ __align__(16) short UMb[16*40];
    __shared__ __align__(16) short U1b[16*40];
    __shared__ __align__(16) short oT [16*264];

    const int tid  = threadIdx.x;
    const int w    = tid >> 6;
    const int lane = tid & 63;
    const int quad = lane >> 4;
    const int m    = lane & 15;
    const int hq   = w*16 + quad*4;
    const int b0   = blockIdx.x * 16;
    const f32x4 z4 = {0.f, 0.f, 0.f, 0.f};
    const float scg[3] = {-LOG2E, LOG2E, 2.0f*LOG2E};   // r, z(flipped), n

    for (int i = tid; i < 16*136; i += 512) yTa[i] = 0;
    for (int i = tid; i < 16*40;  i += 512) { UMb[i] = 0; U1b[i] = 0; }

    f32x4 y = z4;

    // ================= encoder GRU: 1 barrier/step, spread staging =================
    {
        short8 Ehh[3][4];
        #pragma unroll
        for (int g = 0; g < 3; ++g)
            #pragma unroll
            for (int c = 0; c < 4; ++c) {
                const float* ph = W_hh + (size_t)(g*NH + w*16 + m)*NH + c*32 + quad*8;
                short8 fh;
                #pragma unroll
                for (int j = 0; j < 8; ++j) fh[j] = f2bf(scg[g]*ph[j]);
                Ehh[g][c] = fh;
            }
        short8 Eih[3];
        #pragma unroll
        for (int g = 0; g < 3; ++g) {
            short8 f1;
            #pragma unroll
            for (int j = 0; j < 8; ++j) {
                int k = quad*8 + j;
                f1[j] = (k < 12) ? f2bf(scg[g]*W_ih[(size_t)(g*NH + w*16 + m)*12 + k]) : (short)0;
            }
            Eih[g] = f1;
        }
        f32x4 erz4, ezz4, egn4, ein4;
        #pragma unroll
        for (int r = 0; r < 4; ++r) {
            int h = hq + r;
            erz4[r] = -LOG2E*(b_ih[h]      + b_hh[h]);
            ezz4[r] =  LOG2E*(b_ih[NH + h] + b_hh[NH + h]);
            egn4[r] = 2.0f*LOG2E*b_hh[2*NH + h];
            ein4[r] = 2.0f*LOG2E*b_ih[2*NH + h];
        }
        const int eidx = w*24 + lane;
        const int eb = eidx/12, ek = eidx - 12*eb;
        const bool estg = (lane < 24);
        float encv = 0.f;
        if (estg) {
            float e0 = (ek < NKIN) ? pre_x[((size_t)0*NB + b0 + eb)*NKIN + ek]
                                   : pre_y[((size_t)0*NB + b0 + eb)*NKOUT + (ek - NKIN)];
            UMb[eb*40 + ek] = f2bf(e0);
            encv = (ek < NKIN) ? pre_x[((size_t)1*NB + b0 + eb)*NKIN + ek]
                               : pre_y[((size_t)1*NB + b0 + eb)*NKOUT + (ek - NKIN)];
        }
        __syncthreads();
        for (int t = 0; t < NTP; ++t) {
            float evn = 0.f;
            if (estg) {
                int tn = (t + 2 < NTP) ? t + 2 : NTP - 1;
                evn = (ek < NKIN) ? pre_x[((size_t)tn*NB + b0 + eb)*NKIN + ek]
                                  : pre_y[((size_t)tn*NB + b0 + eb)*NKOUT + (ek - NKIN)];
            }
            const short* bin_buf  = (t & 1) ? U1b : UMb;
            short*       bout_buf = (t & 1) ? UMb : U1b;
            const short* sin_buf  = (t & 1) ? yTb : yTa;
            short*       sout_buf = (t & 1) ? yTa : yTb;
            f32x4 gi[3] = {z4, z4, ein4};
            {
                short8 b = *(const short8*)(bin_buf + m*40 + quad*8);
                #pragma unroll
                for (int g = 0; g < 3; ++g)
                    gi[g] = __builtin_amdgcn_mfma_f32_16x16x32_bf16(Eih[g], b, gi[g], 0, 0, 0);
            }
            f32x4 gh[3] = {erz4, ezz4, egn4};
            gemmB(sin_buf + m*136 + quad*8, Ehh, gh);
            f32x4 K;
            gateK(gi, gh, y, K);
            y += K;
            st4(sout_buf + m*136 + hq, y);
            if (estg) { bout_buf[eb*40 + ek] = f2bf(encv); encv = evn; }
            __syncthreads();
        }
    }
    // y(0) in regs; final enc state in yTa (t=63 odd wrote yTa)

    // ---- persistent RK4 A-frags ----
    short8 Ahh[3][4], Aih[3][4];
    #pragma unroll
    for (int g = 0; g < 3; ++g)
        #pragma unroll
        for (int c = 0; c < 4; ++c) {
            const float* ph = Wc_hh + (size_t)(g*NH + w*16 + m)*NH + c*32 + quad*8;
            const float* pi = Wc_ih + (size_t)(g*NH + w*16 + m)*NH + c*32 + quad*8;
            short8 fh, fi;
            #pragma unroll
            for (int j = 0; j < 8; ++j) { fh[j] = f2bf(scg[g]*ph[j]); fi[j] = f2bf(scg[g]*pi[j]); }
            Ahh[g][c] = fh; Aih[g][c] = fi;
        }
    short8 Aexp;
    #pragma unroll
    for (int j = 0; j < 8; ++j) {
        int k = quad*8 + j;
        Aexp[j] = (k < NKIN) ? f2bf(2.0f*LOG2E*W_e[(w*16 + m)*NKIN + k]) : (short)0;
    }
    short8 A1f[2][4];
    #pragma unroll
    for (int kc = 0; kc < 4; ++kc) {
        A1f[0][kc] = *(const short8*)(w1f + (size_t)(((w    )*4 + kc)*64 + lane)*8);
        A1f[1][kc] = *(const short8*)(w1f + (size_t)(((w + 8)*4 + kc)*64 + lane)*8);
    }
    f32x4 brz4, bzz4, bgn4, bin4, be4;
    #pragma unroll
    for (int r = 0; r < 4; ++r) {
        int h = hq + r;
        brz4[r] = -LOG2E*(bc_ih[h]      + bc_hh[h]);
        bzz4[r] =  LOG2E*(bc_ih[NH + h] + bc_hh[NH + h]);
        bgn4[r] = 2.0f*LOG2E*bc_hh[2*NH + h];
        bin4[r] = 2.0f*LOG2E*bc_ih[2*NH + h];
        be4[r]  = 2.0f*LOG2E*b_e[h];
    }

    // ================= in-kernel spline (Thomas, reversed elimination) =================
    // lane<16 of each wave: 128 threads, 1 column each. ys[0]=pre_x[-1], ys[i]=fx[i-1].
    const bool stg = (lane < 16);
    const int sb = w*2 + (lane >> 3), sk = lane & 7;
    const size_t scol = (size_t)(b0 + sb)*NKIN + sk;   // only valid for stg lanes
    float* cpS = (float*)E1;                      // 128 floats, prologue-only use
    float prex_last = 0.f;
    if (stg) prex_last = pre_x[(size_t)(NTP-1)*BKIN + scol];   // guarded: OOB for lane>=16
    if (stg) {
        // pass 1 (j=127..1): e_j = cp[128-j] generated forward; d_j -> UM[j]
        const float r6 = 6.0f/(0.1f*0.1f);
        float c = 0.f, d = 0.f;
        float yp = fx[(size_t)127*BKIN + scol];   // ys[128]
        float y0 = fx[(size_t)126*BKIN + scol];   // ys[127]
        float ym = fx[(size_t)125*BKIN + scol];   // ys[126]
        #pragma unroll 4
        for (int j = 127; j >= 1; --j) {
            float r = r6*(ym - 2.f*y0 + yp);
            c = __builtin_amdgcn_rcpf(4.f - c);
            d = (r - d)*c;
            UM[(size_t)j*BKIN + scol] = d;
            if (tid == 0) cpS[128 - j] = c;
            yp = y0; y0 = ym;
            ym = (j >= 3) ? fx[(size_t)(j-3)*BKIN + scol] : prex_last;
        }
    }
    __syncthreads();   // cpS visible; pass-1 global writes drained
    if (stg) {
        // pass 2 (j=1..127): M_j = d_j - e_j*M_{j-1}; emit UM[j-1]
        const float KK = 0.01f/16.0f;
        float Mp = 0.f;
        float y0 = prex_last;                     // ys[0]
        float y1 = fx[scol];                      // ys[1]
        #pragma unroll 4
        for (int j = 1; j <= 127; ++j) {
            float dj = UM[(size_t)j*BKIN + scol];
            float e  = cpS[128 - j];
            float Mj = dj - e*Mp;
            UM[(size_t)(j-1)*BKIN + scol] = 0.5f*(y0 + y1) - KK*(Mp + Mj);
            Mp = Mj; y0 = y1;
            y1 = fx[(size_t)j*BKIN + scol];       // ys[j+1]
        }
        UM[(size_t)127*BKIN + scol] = 0.5f*(y0 + y1) - KK*Mp;
    }
    __syncthreads();   // UM complete + E1 free again

    // ================= RK4 prologue =================
    if (stg) {   // zero enc cols 8..11 + stage u0_start
        UMb[sb*40 + 8 + (lane & 3)] = 0;
        U1b[sb*40 + 8 + (lane & 3)] = 0;
        UMb[sb*40 + sk] = f2bf(prex_last);
    }
    __syncthreads();
    {   // x0 = tanh-expand(u0_start) -> xmT
        short8 b = *(const short8*)(UMb + m*40 + quad*8);
        f32x4 c0 = be4;
        c0 = __builtin_amdgcn_mfma_f32_16x16x32_bf16(Aexp, b, c0, 0, 0, 0);
        f32x4 xv = 1.0f - 2.0f*rcp4(exp24(c0) + 1.0f);
        st4(xmT + m*136 + hq, xv);
    }
    __syncthreads();
    f32x4 gi0[3] = {z4, z4, bin4};
    gemmB(xmT + m*136 + quad*8, Aih, gi0);
    if (stg) { UMb[sb*40 + sk] = f2bf(UM[scol]); U1b[sb*40 + sk] = f2bf(fx[scol]); }
    __syncthreads();
    {   // expand u(0) -> xmT, x1T
        short8 bm = *(const short8*)(UMb + m*40 + quad*8);
        short8 b1 = *(const short8*)(U1b + m*40 + quad*8);
        f32x4 cm = be4, c1 = be4;
        cm = __builtin_amdgcn_mfma_f32_16x16x32_bf16(Aexp, bm, cm, 0, 0, 0);
        c1 = __builtin_amdgcn_mfma_f32_16x16x32_bf16(Aexp, b1, c1, 0, 0, 0);
        f32x4 xm = 1.0f - 2.0f*rcp4(exp24(cm) + 1.0f);
        f32x4 x1 = 1.0f - 2.0f*rcp4(exp24(c1) + 1.0f);
        st4(xmT + m*136 + hq, xm);
        st4(x1T + m*136 + hq, x1);
    }
    float fxv = 0.f, umv = 0.f;
    if (stg) { fxv = fx[(size_t)BKIN + scol]; umv = UM[(size_t)BKIN + scol]; }  // u(1)
    __syncthreads();
    f32x4 gim[3] = {z4, z4, bin4}, gi1[3] = {z4, z4, bin4};
    gemmB(xmT + m*136 + quad*8, Aih, gim);
    gemmB(x1T + m*136 + quad*8, Aih, gi1);

    // ================= RK4 loop: 5 barriers/step (R3-shape) =================
    for (int st = 0; st < NL; ++st) {
        // ---- P1: k1 ----
        f32x4 gh[3] = {brz4, bzz4, bgn4};
        gemmB(yTa + m*136 + quad*8, Ahh, gh);
        f32x4 K, Ks, ye;
        gateK(gi0, gh, y, K);
        Ks = K; ye = y + 0.5f*K;
        st4(yTb + m*136 + hq, ye);
        __syncthreads();                                        // B1
        // ---- P2: k2 ----
        gh[0] = brz4; gh[1] = bzz4; gh[2] = bgn4;
        gemmB(yTb + m*136 + quad*8, Ahh, gh);
        gateK(gim, gh, ye, K);
        Ks += 2.0f*K; ye = y + 0.5f*K;
        st4(E1 + m*136 + hq, ye);
        __syncthreads();                                        // B2
        // ---- P3: k3 ----
        gh[0] = brz4; gh[1] = bzz4; gh[2] = bgn4;
        gemmB(E1 + m*136 + quad*8, Ahh, gh);
        gateK(gim, gh, ye, K);
        Ks += 2.0f*K; ye = y + K;
        st4(yTb + m*136 + hq, ye);
        __syncthreads();                                        // B3
        // ---- P4: k4 + y update + staging u(st+1) ----
        if (stg) { UMb[sb*40 + sk] = f2bf(umv); U1b[sb*40 + sk] = f2bf(fxv); }
        gh[0] = brz4; gh[1] = bzz4; gh[2] = bgn4;
        gemmB(yTb + m*136 + quad*8, Ahh, gh);
        gateK(gi1, gh, ye, K);
        y += (1.0f/6.0f)*(Ks + K);
        st4(yTa + m*136 + hq, y);
        __syncthreads();                                        // B4
        // ---- P5: head1(st) + expand(st+1) + prefetch u(st+2) ----
        if (stg) {
            int sn = (st + 2 < NL) ? st + 2 : NL - 1;
            fxv = fx[(size_t)sn*BKIN + scol];
            umv = UM[(size_t)sn*BKIN + scol];
        }
        {
            short8 byf[4];
            ld4(yTa + m*136 + quad*8, byf);
            f32x4 o0 = z4, o1 = z4;
            #pragma unroll
            for (int kc = 0; kc < 4; ++kc) {
                o0 = __builtin_amdgcn_mfma_f32_16x16x32_bf16(A1f[0][kc], byf[kc], o0, 0, 0, 0);
                o1 = __builtin_amdgcn_mfma_f32_16x16x32_bf16(A1f[1][kc], byf[kc], o1, 0, 0, 0);
            }
            f32x4 t0 = 1.0f - 2.0f*rcp4(exp24(o0) + 1.0f);
            f32x4 t1 = 1.0f - 2.0f*rcp4(exp24(o1) + 1.0f);
            st4(oT + m*264 + w*16     + quad*4, t0);
            st4(oT + m*264 + (w+8)*16 + quad*4, t1);
        }
        {   // expand u(st+1)
            short8 bm = *(const short8*)(UMb + m*40 + quad*8);
            short8 b1 = *(const short8*)(U1b + m*40 + quad*8);
            f32x4 cm = be4, c1 = be4;
            cm = __builtin_amdgcn_mfma_f32_16x16x32_bf16(Aexp, bm, cm, 0, 0, 0);
            c1 = __builtin_amdgcn_mfma_f32_16x16x32_bf16(Aexp, b1, c1, 0, 0, 0);
            f32x4 xm = 1.0f - 2.0f*rcp4(exp24(cm) + 1.0f);
            f32x4 x1 = 1.0f - 2.0f*rcp4(exp24(c1) + 1.0f);
            st4(xmT + m*136 + hq, xm);
            st4(x1T + m*136 + hq, x1);
        }
        __syncthreads();                                        // B5
        // ---- tail (no barrier): stage2(st) + gi for st+1 ----
        if (w == (st & 7)) {
            short8 a2f[8];
            #pragma unroll
            for (int kc = 0; kc < 8; ++kc)
                a2f[kc] = *(const short8*)(w2f + (size_t)(kc*64 + lane)*8);
            f32x4 oc = z4;
            #pragma unroll
            for (int kc = 0; kc < 8; ++kc) {
                short8 b = *(const short8*)(oT + m*264 + kc*32 + quad*8);
                oc = __builtin_amdgcn_mfma_f32_16x16x32_bf16(a2f[kc], b, oc, 0, 0, 0);
            }
            if (quad == 0)
                *(f32x4*)(out + ((size_t)st*NB + b0 + m)*NKOUT) = oc;
        }
        gi0[0] = gi1[0]; gi0[1] = gi1[1]; gi0[2] = gi1[2];
        gim[0] = z4; gim[1] = z4; gim[2] = bin4;
        gi1[0] = z4; gi1[1] = z4; gi1[2] = bin4;
        gemmB(xmT + m*136 + quad*8, Aih, gim);
        gemmB(x1T + m*136 + quad*8, Aih, gi1);
    }
}

extern "C" void kernel_launch(void* const* d_in, const int* in_sizes, int n_in,
                              void* d_out, int out_size, void* d_ws, size_t ws_size,
                              hipStream_t stream)
{
    const float* pre_x = (const float*)d_in[0];
    const float* pre_y = (const float*)d_in[1];
    const float* fx    = (const float*)d_in[2];
    const float* W_ih  = (const float*)d_in[3];
    const float* W_hh  = (const float*)d_in[4];
    const float* b_ih  = (const float*)d_in[5];
    const float* b_hh  = (const float*)d_in[6];
    const float* W_e   = (const float*)d_in[7];
    const float* b_e   = (const float*)d_in[8];
    const float* Wc_ih = (const float*)d_in[9];
    const float* Wc_hh = (const float*)d_in[10];
    const float* bc_ih = (const float*)d_in[11];
    const float* bc_hh = (const float*)d_in[12];
    const float* W1    = (const float*)d_in[13];
    const float* W2    = (const float*)d_in[14];
    float* out = (float*)d_out;

    float* UM  = (float*)d_ws;                                  // 128*4096*8 fp32 = 16.78 MB
    short* w1f = (short*)((char*)d_ws + (size_t)NL*NB*NKIN*4);  // 32768 shorts
    short* w2f = w1f + 16*4*64*8;                               // 4096 shorts

    prep_frags<<<dim3(8), dim3(256), 0, stream>>>(W1, W2, w1f, w2f);
    fused_kernel<<<dim3(NB/16), dim3(512), 0, stream>>>(
        pre_x, pre_y, fx, W_ih, W_hh, b_ih, b_hh, W_e, b_e,
        Wc_ih, Wc_hh, bc_ih, bc_hh, UM, w1f, w2f, out);
}

// Round 8
// 705.283 us; speedup vs baseline: 1.1955x; 1.0167x over previous
//
#include <hip/hip_runtime.h>
#include <math.h>

#define NB    4096
#define NH    128
#define NKIN  8
#define NKOUT 4
#define NTP   64
#define NL    128
#define BKIN  (NB*NKIN)
#define LOG2E 1.44269504088896340736f

// lgkm-only barrier: orders LDS ops across the block WITHOUT draining in-flight
// global loads (compiler's __syncthreads emits s_waitcnt vmcnt(0) which exposes
// prefetch latency every phase). Safe here: loops have no cross-thread global deps.
#define BAR() asm volatile("s_waitcnt lgkmcnt(0)\n\ts_barrier" ::: "memory")

typedef __attribute__((ext_vector_type(8))) short short8;
typedef __attribute__((ext_vector_type(4))) float f32x4;

#if __has_builtin(__builtin_amdgcn_exp2f)
#define EXP2F __builtin_amdgcn_exp2f
#else
#define EXP2F exp2f
#endif

__device__ __forceinline__ short f2bf(float f) {
    union { float f; unsigned u; } v; v.f = f;
    unsigned u = v.u;
    return (short)((u + 0x7fffu + ((u >> 16) & 1u)) >> 16);
}
__device__ __forceinline__ unsigned pkbf2(float a, float b) {
#if __has_builtin(__builtin_amdgcn_cvt_pk_bf16_f32)
    auto p = __builtin_amdgcn_cvt_pk_bf16_f32(a, b);
    unsigned q; __builtin_memcpy(&q, &p, 4); return q;
#else
    union { float f; unsigned u; } x, y; x.f = a; y.f = b;
    unsigned ua = (x.u + 0x7fffu + ((x.u >> 16) & 1u)) >> 16;
    unsigned ub = (y.u + 0x7fffu + ((y.u >> 16) & 1u)) & 0xffff0000u;
    return ua | ub;
#endif
}
__device__ __forceinline__ void st4(short* dst, const f32x4& v) {
    uint2 q; q.x = pkbf2(v[0], v[1]); q.y = pkbf2(v[2], v[3]);
    *(uint2*)dst = q;
}
__device__ __forceinline__ f32x4 exp24(f32x4 a) {
    f32x4 r;
    #pragma unroll
    for (int i = 0; i < 4; ++i) r[i] = EXP2F(a[i]);
    return r;
}
__device__ __forceinline__ f32x4 rcp4(f32x4 a) {
    f32x4 r;
    #pragma unroll
    for (int i = 0; i < 4; ++i) r[i] = __builtin_amdgcn_rcpf(a[i]);
    return r;
}

// ---------------- prep: W1/W2 as A-operand fragments (bf16, W1 pre-scaled) ----
__global__ void prep_frags(const float* __restrict__ W1, const float* __restrict__ W2,
                           short* __restrict__ w1f, short* __restrict__ w2f)
{
    int tid0 = blockIdx.x*256 + threadIdx.x;
    for (int idx = tid0; idx < 16*4*64*8; idx += 8*256) {
        int j = idx & 7, lane = (idx >> 3) & 63, kc = (idx >> 9) & 3, t = idx >> 11;
        int row = t*16 + (lane & 15);
        int k   = kc*32 + (lane >> 4)*8 + j;
        w1f[idx] = f2bf(2.0f*LOG2E*W1[row*NH + k]);
    }
    for (int idx = tid0; idx < 8*64*8; idx += 8*256) {
        int j = idx & 7, lane = (idx >> 3) & 63, kc = idx >> 9;
        int m = lane & 15;
        int k = kc*32 + (lane >> 4)*8 + j;
        w2f[idx] = (m < NKOUT) ? f2bf(W2[m*2*NH + k]) : (short)0;
    }
}

// ---------------- fused kernel helpers ----------------
__device__ __forceinline__ void ld4(const short* bp, short8 (&bf)[4]) {
    #pragma unroll
    for (int kc = 0; kc < 4; ++kc) bf[kc] = *(const short8*)(bp + kc*32);
}
__device__ __forceinline__ void gemmR(const short8 (&bf)[4], const short8 (&A)[3][4],
                                      f32x4 (&acc)[3]) {
    #pragma unroll
    for (int kc = 0; kc < 4; ++kc)
        #pragma unroll
        for (int g = 0; g < 3; ++g)
            acc[g] = __builtin_amdgcn_mfma_f32_16x16x32_bf16(A[g][kc], bf[kc], acc[g], 0, 0, 0);
}
__device__ __forceinline__ void gemmB(const short* bp, const short8 (&A)[3][4], f32x4 (&acc)[3]) {
    short8 bf[4]; ld4(bp, bf); gemmR(bf, A, acc);
}
// r-gate scaled -LOG2E (rg = sigmoid), z-gate scaled +LOG2E (zc = 1-z),
// n-gate scaled 2*LOG2E (tanh). K = (1-z)*(n - y).
__device__ __forceinline__ void gateK(const f32x4 (&gi)[3], const f32x4 (&gh)[3],
                                      const f32x4& yin, f32x4& K)
{
    f32x4 rg = rcp4(exp24(gi[0] + gh[0]) + 1.0f);
    f32x4 zc = rcp4(exp24(gi[1] + gh[1]) + 1.0f);
    f32x4 tg = 1.0f - 2.0f*rcp4(exp24(gi[2] + rg*gh[2]) + 1.0f);
    K = zc*(tg - yin);
}

__global__ void __launch_bounds__(512, 2)
fused_kernel(const float* __restrict__ pre_x, const float* __restrict__ pre_y,
             const float* __restrict__ fx,
             const float* __restrict__ W_ih, const float* __restrict__ W_hh,
             const float* __restrict__ b_ih, const float* __restrict__ b_hh,
             const float* __restrict__ W_e,  const float* __restrict__ b_e,
             const float* __restrict__ Wc_ih,const float* __restrict__ Wc_hh,
             const float* __restrict__ bc_ih,const float* __restrict__ bc_hh,
             float* __restrict__ UM,         const short* __restrict__ w1f,
             const short* __restrict__ w2f,  float* __restrict__ out)
{
    __shared__ __align__(16) short yTa[16*136];   // enc ping / RK4 y
    __shared__ __align__(16) short yTb[16*136];   // enc pong / RK4 ye1, ye3
    __shared__ __align__(16) short E1 [16*136];   // spline cp (prologue) / ye2
    __shared__ __align__(16) short xmT[16*136];
    __shared__ __align__(16) short x1T[16*136];
    __shared__ __align__(16) short UMb[16*40];
    __shared__ __align__(16) short U1b[16*40];
    __shared__ __align__(16) short oT [16*264];
    __shared__ __align__(16) short w2S[8*64*8];   // W2 A-frags resident in LDS (8 KB)

    const int tid  = threadIdx.x;
    const int w    = tid >> 6;
    const int lane = tid & 63;
    const int quad = lane >> 4;
    const int m    = lane & 15;
    const int hq   = w*16 + quad*4;
    const int b0   = blockIdx.x * 16;
    const f32x4 z4 = {0.f, 0.f, 0.f, 0.f};
    const float scg[3] = {-LOG2E, LOG2E, 2.0f*LOG2E};   // r, z(flipped), n

    for (int i = tid; i < 16*136; i += 512) yTa[i] = 0;
    for (int i = tid; i < 16*40;  i += 512) { UMb[i] = 0; U1b[i] = 0; }
    ((short8*)w2S)[tid & 511] = ((const short8*)w2f)[tid & 511];   // 512 frags, 1/thread

    f32x4 y = z4;

    // ================= encoder GRU: 1 fast barrier/step =================
    {
        short8 Ehh[3][4];
        #pragma unroll
        for (int g = 0; g < 3; ++g)
            #pragma unroll
            for (int c = 0; c < 4; ++c) {
                const float* ph = W_hh + (size_t)(g*NH + w*16 + m)*NH + c*32 + quad*8;
                short8 fh;
                #pragma unroll
                for (int j = 0; j < 8; ++j) fh[j] = f2bf(scg[g]*ph[j]);
                Ehh[g][c] = fh;
            }
        short8 Eih[3];
        #pragma unroll
        for (int g = 0; g < 3; ++g) {
            short8 f1;
            #pragma unroll
            for (int j = 0; j < 8; ++j) {
                int k = quad*8 + j;
                f1[j] = (k < 12) ? f2bf(scg[g]*W_ih[(size_t)(g*NH + w*16 + m)*12 + k]) : (short)0;
            }
            Eih[g] = f1;
        }
        f32x4 erz4, ezz4, egn4, ein4;
        #pragma unroll
        for (int r = 0; r < 4; ++r) {
            int h = hq + r;
            erz4[r] = -LOG2E*(b_ih[h]      + b_hh[h]);
            ezz4[r] =  LOG2E*(b_ih[NH + h] + b_hh[NH + h]);
            egn4[r] = 2.0f*LOG2E*b_hh[2*NH + h];
            ein4[r] = 2.0f*LOG2E*b_ih[2*NH + h];
        }
        const int eidx = w*24 + lane;
        const int eb = eidx/12, ek = eidx - 12*eb;
        const bool estg = (lane < 24);
        float encv = 0.f;
        if (estg) {
            float e0 = (ek < NKIN) ? pre_x[((size_t)0*NB + b0 + eb)*NKIN + ek]
                                   : pre_y[((size_t)0*NB + b0 + eb)*NKOUT + (ek - NKIN)];
            UMb[eb*40 + ek] = f2bf(e0);
            encv = (ek < NKIN) ? pre_x[((size_t)1*NB + b0 + eb)*NKIN + ek]
                               : pre_y[((size_t)1*NB + b0 + eb)*NKOUT + (ek - NKIN)];
        }
        BAR();
        for (int t = 0; t < NTP; ++t) {
            float evn = 0.f;
            if (estg) {                      // prefetch input(t+2); stays in flight (no vmcnt drain)
                int tn = (t + 2 < NTP) ? t + 2 : NTP - 1;
                evn = (ek < NKIN) ? pre_x[((size_t)tn*NB + b0 + eb)*NKIN + ek]
                                  : pre_y[((size_t)tn*NB + b0 + eb)*NKOUT + (ek - NKIN)];
            }
            const short* bin_buf  = (t & 1) ? U1b : UMb;
            short*       bout_buf = (t & 1) ? UMb : U1b;
            const short* sin_buf  = (t & 1) ? yTb : yTa;
            short*       sout_buf = (t & 1) ? yTa : yTb;
            f32x4 gi[3] = {z4, z4, ein4};
            {
                short8 b = *(const short8*)(bin_buf + m*40 + quad*8);
                #pragma unroll
                for (int g = 0; g < 3; ++g)
                    gi[g] = __builtin_amdgcn_mfma_f32_16x16x32_bf16(Eih[g], b, gi[g], 0, 0, 0);
            }
            f32x4 gh[3] = {erz4, ezz4, egn4};
            gemmB(sin_buf + m*136 + quad*8, Ehh, gh);
            f32x4 K;
            gateK(gi, gh, y, K);
            y += K;
            st4(sout_buf + m*136 + hq, y);
            if (estg) { bout_buf[eb*40 + ek] = f2bf(encv); encv = evn; }
            BAR();
        }
    }
    // y(0) in regs; final enc state in yTa (t=63 odd wrote yTa)

    // ---- persistent RK4 A-frags ----
    short8 Ahh[3][4], Aih[3][4];
    #pragma unroll
    for (int g = 0; g < 3; ++g)
        #pragma unroll
        for (int c = 0; c < 4; ++c) {
            const float* ph = Wc_hh + (size_t)(g*NH + w*16 + m)*NH + c*32 + quad*8;
            const float* pi = Wc_ih + (size_t)(g*NH + w*16 + m)*NH + c*32 + quad*8;
            short8 fh, fi;
            #pragma unroll
            for (int j = 0; j < 8; ++j) { fh[j] = f2bf(scg[g]*ph[j]); fi[j] = f2bf(scg[g]*pi[j]); }
            Ahh[g][c] = fh; Aih[g][c] = fi;
        }
    short8 Aexp;
    #pragma unroll
    for (int j = 0; j < 8; ++j) {
        int k = quad*8 + j;
        Aexp[j] = (k < NKIN) ? f2bf(2.0f*LOG2E*W_e[(w*16 + m)*NKIN + k]) : (short)0;
    }
    short8 A1f[2][4];
    #pragma unroll
    for (int kc = 0; kc < 4; ++kc) {
        A1f[0][kc] = *(const short8*)(w1f + (size_t)(((w    )*4 + kc)*64 + lane)*8);
        A1f[1][kc] = *(const short8*)(w1f + (size_t)(((w + 8)*4 + kc)*64 + lane)*8);
    }
    f32x4 brz4, bzz4, bgn4, bin4, be4;
    #pragma unroll
    for (int r = 0; r < 4; ++r) {
        int h = hq + r;
        brz4[r] = -LOG2E*(bc_ih[h]      + bc_hh[h]);
        bzz4[r] =  LOG2E*(bc_ih[NH + h] + bc_hh[NH + h]);
        bgn4[r] = 2.0f*LOG2E*bc_hh[2*NH + h];
        bin4[r] = 2.0f*LOG2E*bc_ih[2*NH + h];
        be4[r]  = 2.0f*LOG2E*b_e[h];
    }

    // ================= in-kernel spline (Thomas, reversed elimination) =================
    // lane<16 of each wave: 128 threads, 1 column each. ys[0]=pre_x[-1], ys[i]=fx[i-1].
    const bool stg = (lane < 16);
    const int sb = w*2 + (lane >> 3), sk = lane & 7;
    const size_t scol = (size_t)(b0 + sb)*NKIN + sk;   // only valid for stg lanes
    float* cpS = (float*)E1;                      // 128 floats, prologue-only use
    float prex_last = 0.f;
    if (stg) prex_last = pre_x[(size_t)(NTP-1)*BKIN + scol];   // guarded (OOB for lane>=16)
    if (stg) {
        // pass 1 (j=127..1): e_j = cp[128-j] generated forward; d_j -> UM[j]
        const float r6 = 6.0f/(0.1f*0.1f);
        float c = 0.f, d = 0.f;
        float yp = fx[(size_t)127*BKIN + scol];   // ys[128]
        float y0 = fx[(size_t)126*BKIN + scol];   // ys[127]
        float ym = fx[(size_t)125*BKIN + scol];   // ys[126]
        #pragma unroll 4
        for (int j = 127; j >= 1; --j) {
            float r = r6*(ym - 2.f*y0 + yp);
            c = __builtin_amdgcn_rcpf(4.f - c);
            d = (r - d)*c;
            UM[(size_t)j*BKIN + scol] = d;
            if (tid == 0) cpS[128 - j] = c;
            yp = y0; y0 = ym;
            ym = (j >= 3) ? fx[(size_t)(j-3)*BKIN + scol] : prex_last;
        }
    }
    __syncthreads();   // FULL barrier: same-thread global RAW on UM (pass1 -> pass2)
    if (stg) {
        // pass 2 (j=1..127): M_j = d_j - e_j*M_{j-1}; emit UM[j-1]
        const float KK = 0.01f/16.0f;
        float Mp = 0.f;
        float y0 = prex_last;                     // ys[0]
        float y1 = fx[scol];                      // ys[1]
        #pragma unroll 4
        for (int j = 1; j <= 127; ++j) {
            float dj = UM[(size_t)j*BKIN + scol];
            float e  = cpS[128 - j];
            float Mj = dj - e*Mp;
            UM[(size_t)(j-1)*BKIN + scol] = 0.5f*(y0 + y1) - KK*(Mp + Mj);
            Mp = Mj; y0 = y1;
            y1 = fx[(size_t)j*BKIN + scol];       // ys[j+1]
        }
        UM[(size_t)127*BKIN + scol] = 0.5f*(y0 + y1) - KK*Mp;
    }
    __syncthreads();   // FULL barrier: UM writes drained before RK4 reads; E1 free again

    // ================= RK4 prologue =================
    if (stg) {   // zero enc cols 8..11 + stage u0_start
        UMb[sb*40 + 8 + (lane & 3)] = 0;
        U1b[sb*40 + 8 + (lane & 3)] = 0;
        UMb[sb*40 + sk] = f2bf(prex_last);
    }
    BAR();
    {   // x0 = tanh-expand(u0_start) -> xmT
        short8 b = *(const short8*)(UMb + m*40 + quad*8);
        f32x4 c0 = be4;
        c0 = __builtin_amdgcn_mfma_f32_16x16x32_bf16(Aexp, b, c0, 0, 0, 0);
        f32x4 xv = 1.0f - 2.0f*rcp4(exp24(c0) + 1.0f);
        st4(xmT + m*136 + hq, xv);
    }
    BAR();
    f32x4 gi0[3] = {z4, z4, bin4};
    gemmB(xmT + m*136 + quad*8, Aih, gi0);
    if (stg) { UMb[sb*40 + sk] = f2bf(UM[scol]); U1b[sb*40 + sk] = f2bf(fx[scol]); }
    BAR();
    {   // expand u(0) -> xmT, x1T
        short8 bm = *(const short8*)(UMb + m*40 + quad*8);
        short8 b1 = *(const short8*)(U1b + m*40 + quad*8);
        f32x4 cm = be4, c1 = be4;
        cm = __builtin_amdgcn_mfma_f32_16x16x32_bf16(Aexp, bm, cm, 0, 0, 0);
        c1 = __builtin_amdgcn_mfma_f32_16x16x32_bf16(Aexp, b1, c1, 0, 0, 0);
        f32x4 xm = 1.0f - 2.0f*rcp4(exp24(cm) + 1.0f);
        f32x4 x1 = 1.0f - 2.0f*rcp4(exp24(c1) + 1.0f);
        st4(xmT + m*136 + hq, xm);
        st4(x1T + m*136 + hq, x1);
    }
    float fxv = 0.f, umv = 0.f;
    if (stg) { fxv = fx[(size_t)BKIN + scol]; umv = UM[(size_t)BKIN + scol]; }  // u(1)
    BAR();
    f32x4 gim[3] = {z4, z4, bin4}, gi1[3] = {z4, z4, bin4};
    gemmB(xmT + m*136 + quad*8, Aih, gim);
    gemmB(x1T + m*136 + quad*8, Aih, gi1);

    // ================= RK4 loop: 5 fast barriers/step (R3-shape) =================
    for (int st = 0; st < NL; ++st) {
        // ---- P1: k1 ----
        f32x4 gh[3] = {brz4, bzz4, bgn4};
        gemmB(yTa + m*136 + quad*8, Ahh, gh);
        f32x4 K, Ks, ye;
        gateK(gi0, gh, y, K);
        Ks = K; ye = y + 0.5f*K;
        st4(yTb + m*136 + hq, ye);
        BAR();                                                  // B1
        // ---- P2: k2 ----
        gh[0] = brz4; gh[1] = bzz4; gh[2] = bgn4;
        gemmB(yTb + m*136 + quad*8, Ahh, gh);
        gateK(gim, gh, ye, K);
        Ks += 2.0f*K; ye = y + 0.5f*K;
        st4(E1 + m*136 + hq, ye);
        BAR();                                                  // B2
        // ---- P3: k3 ----
        gh[0] = brz4; gh[1] = bzz4; gh[2] = bgn4;
        gemmB(E1 + m*136 + quad*8, Ahh, gh);
        gateK(gim, gh, ye, K);
        Ks += 2.0f*K; ye = y + K;
        st4(yTb + m*136 + hq, ye);
        BAR();                                                  // B3
        // ---- P4: k4 + y update + staging u(st+1) ----
        if (stg) { UMb[sb*40 + sk] = f2bf(umv); U1b[sb*40 + sk] = f2bf(fxv); }
        gh[0] = brz4; gh[1] = bzz4; gh[2] = bgn4;
        gemmB(yTb + m*136 + quad*8, Ahh, gh);
        gateK(gi1, gh, ye, K);
        y += (1.0f/6.0f)*(Ks + K);
        st4(yTa + m*136 + hq, y);
        BAR();                                                  // B4
        // ---- P5: head1(st) + expand(st+1) + prefetch u(st+2) ----
        if (stg) {                     // loads stay in flight across B5..B3 (consumed in P4)
            int sn = (st + 2 < NL) ? st + 2 : NL - 1;
            fxv = fx[(size_t)sn*BKIN + scol];
            umv = UM[(size_t)sn*BKIN + scol];
        }
        {
            short8 byf[4];
            ld4(yTa + m*136 + quad*8, byf);
            f32x4 o0 = z4, o1 = z4;
            #pragma unroll
            for (int kc = 0; kc < 4; ++kc) {
                o0 = __builtin_amdgcn_mfma_f32_16x16x32_bf16(A1f[0][kc], byf[kc], o0, 0, 0, 0);
                o1 = __builtin_amdgcn_mfma_f32_16x16x32_bf16(A1f[1][kc], byf[kc], o1, 0, 0, 0);
            }
            f32x4 t0 = 1.0f - 2.0f*rcp4(exp24(o0) + 1.0f);
            f32x4 t1 = 1.0f - 2.0f*rcp4(exp24(o1) + 1.0f);
            st4(oT + m*264 + w*16     + quad*4, t0);
            st4(oT + m*264 + (w+8)*16 + quad*4, t1);
        }
        {   // expand u(st+1)
            short8 bm = *(const short8*)(UMb + m*40 + quad*8);
            short8 b1 = *(const short8*)(U1b + m*40 + quad*8);
            f32x4 cm = be4, c1 = be4;
            cm = __builtin_amdgcn_mfma_f32_16x16x32_bf16(Aexp, bm, cm, 0, 0, 0);
            c1 = __builtin_amdgcn_mfma_f32_16x16x32_bf16(Aexp, b1, c1, 0, 0, 0);
            f32x4 xm = 1.0f - 2.0f*rcp4(exp24(cm) + 1.0f);
            f32x4 x1 = 1.0f - 2.0f*rcp4(exp24(c1) + 1.0f);
            st4(xmT + m*136 + hq, xm);
            st4(x1T + m*136 + hq, x1);
        }
        BAR();                                                  // B5
        // ---- tail (no barrier): stage2(st) from LDS + gi for st+1 ----
        if (w == (st & 7)) {
            f32x4 oc = z4;
            #pragma unroll
            for (int kc = 0; kc < 8; ++kc) {
                short8 a2 = *(const short8*)(w2S + (kc*64 + lane)*8);
                short8 b  = *(const short8*)(oT + m*264 + kc*32 + quad*8);
                oc = __builtin_amdgcn_mfma_f32_16x16x32_bf16(a2, b, oc, 0, 0, 0);
            }
            if (quad == 0)
                *(f32x4*)(out + ((size_t)st*NB + b0 + m)*NKOUT) = oc;
        }
        gi0[0] = gi1[0]; gi0[1] = gi1[1]; gi0[2] = gi1[2];
        gim[0] = z4; gim[1] = z4; gim[2] = bin4;
        gi1[0] = z4; gi1[1] = z4; gi1[2] = bin4;
        gemmB(xmT + m*136 + quad*8, Aih, gim);
        gemmB(x1T + m*136 + quad*8, Aih, gi1);
    }
}

extern "C" void kernel_launch(void* const* d_in, const int* in_sizes, int n_in,
                              void* d_out, int out_size, void* d_ws, size_t ws_size,
                              hipStream_t stream)
{
    const float* pre_x = (const float*)d_in[0];
    const float* pre_y = (const float*)d_in[1];
    const float* fx    = (const float*)d_in[2];
    const float* W_ih  = (const float*)d_in[3];
    const float* W_hh  = (const float*)d_in[4];
    const float* b_ih  = (const float*)d_in[5];
    const float* b_hh  = (const float*)d_in[6];
    const float* W_e   = (const float*)d_in[7];
    const float* b_e   = (const float*)d_in[8];
    const float* Wc_ih = (const float*)d_in[9];
    const float* Wc_hh = (const float*)d_in[10];
    const float* bc_ih = (const float*)d_in[11];
    const float* bc_hh = (const float*)d_in[12];
    const float* W1    = (const float*)d_in[13];
    const float* W2    = (const float*)d_in[14];
    float* out = (float*)d_out;

    float* UM  = (float*)d_ws;                                  // 128*4096*8 fp32 = 16.78 MB
    short* w1f = (short*)((char*)d_ws + (size_t)NL*NB*NKIN*4);  // 32768 shorts
    short* w2f = w1f + 16*4*64*8;                               // 4096 shorts

    prep_frags<<<dim3(8), dim3(256), 0, stream>>>(W1, W2, w1f, w2f);
    fused_kernel<<<dim3(NB/16), dim3(512), 0, stream>>>(
        pre_x, pre_y, fx, W_ih, W_hh, b_ih, b_hh, W_e, b_e,
        Wc_ih, Wc_hh, bc_ih, bc_hh, UM, w1f, w2f, out);
}

// Round 9
// 685.005 us; speedup vs baseline: 1.2309x; 1.0296x over previous
//
#include <hip/hip_runtime.h>
#include <math.h>

#define NB    4096
#define NH    128
#define NKIN  8
#define NKOUT 4
#define NTP   64
#define NL    128
#define BKIN  (NB*NKIN)
#define LOG2E 1.44269504088896340736f

// lgkm-only barrier: orders LDS ops across the block WITHOUT draining in-flight
// global loads. Safe: loops have no cross-thread global dependencies.
#define BAR() asm volatile("s_waitcnt lgkmcnt(0)\n\ts_barrier" ::: "memory")

typedef __attribute__((ext_vector_type(8))) short short8;
typedef __attribute__((ext_vector_type(4))) float f32x4;

#if __has_builtin(__builtin_amdgcn_exp2f)
#define EXP2F __builtin_amdgcn_exp2f
#else
#define EXP2F exp2f
#endif

__device__ __forceinline__ short f2bf(float f) {
    union { float f; unsigned u; } v; v.f = f;
    unsigned u = v.u;
    return (short)((u + 0x7fffu + ((u >> 16) & 1u)) >> 16);
}
__device__ __forceinline__ unsigned pkbf2(float a, float b) {
#if __has_builtin(__builtin_amdgcn_cvt_pk_bf16_f32)
    auto p = __builtin_amdgcn_cvt_pk_bf16_f32(a, b);
    unsigned q; __builtin_memcpy(&q, &p, 4); return q;
#else
    union { float f; unsigned u; } x, y; x.f = a; y.f = b;
    unsigned ua = (x.u + 0x7fffu + ((x.u >> 16) & 1u)) >> 16;
    unsigned ub = (y.u + 0x7fffu + ((y.u >> 16) & 1u)) & 0xffff0000u;
    return ua | ub;
#endif
}
__device__ __forceinline__ void st4(short* dst, const f32x4& v) {
    uint2 q; q.x = pkbf2(v[0], v[1]); q.y = pkbf2(v[2], v[3]);
    *(uint2*)dst = q;
}
__device__ __forceinline__ f32x4 exp24(f32x4 a) {
    f32x4 r;
    #pragma unroll
    for (int i = 0; i < 4; ++i) r[i] = EXP2F(a[i]);
    return r;
}
__device__ __forceinline__ f32x4 rcp4(f32x4 a) {
    f32x4 r;
    #pragma unroll
    for (int i = 0; i < 4; ++i) r[i] = __builtin_amdgcn_rcpf(a[i]);
    return r;
}

// ---------------- prep: W1/W2 as A-operand fragments (bf16, W1 pre-scaled) ----
__global__ void prep_frags(const float* __restrict__ W1, const float* __restrict__ W2,
                           short* __restrict__ w1f, short* __restrict__ w2f)
{
    int tid0 = blockIdx.x*256 + threadIdx.x;
    for (int idx = tid0; idx < 16*4*64*8; idx += 8*256) {
        int j = idx & 7, lane = (idx >> 3) & 63, kc = (idx >> 9) & 3, t = idx >> 11;
        int row = t*16 + (lane & 15);
        int k   = kc*32 + (lane >> 4)*8 + j;
        w1f[idx] = f2bf(2.0f*LOG2E*W1[row*NH + k]);
    }
    for (int idx = tid0; idx < 8*64*8; idx += 8*256) {
        int j = idx & 7, lane = (idx >> 3) & 63, kc = idx >> 9;
        int m = lane & 15;
        int k = kc*32 + (lane >> 4)*8 + j;
        w2f[idx] = (m < NKOUT) ? f2bf(W2[m*2*NH + k]) : (short)0;
    }
}

// ---------------- fused kernel helpers ----------------
__device__ __forceinline__ void ld4(const short* bp, short8 (&bf)[4]) {
    #pragma unroll
    for (int kc = 0; kc < 4; ++kc) bf[kc] = *(const short8*)(bp + kc*32);
}
__device__ __forceinline__ void gemmR(const short8 (&bf)[4], const short8 (&A)[3][4],
                                      f32x4 (&acc)[3]) {
    #pragma unroll
    for (int kc = 0; kc < 4; ++kc)
        #pragma unroll
        for (int g = 0; g < 3; ++g)
            acc[g] = __builtin_amdgcn_mfma_f32_16x16x32_bf16(A[g][kc], bf[kc], acc[g], 0, 0, 0);
}
__device__ __forceinline__ void gemmB(const short* bp, const short8 (&A)[3][4], f32x4 (&acc)[3]) {
    short8 bf[4]; ld4(bp, bf); gemmR(bf, A, acc);
}
// r-gate scaled -LOG2E (rg = sigmoid), z-gate scaled +LOG2E (zc = 1-z),
// n-gate scaled 2*LOG2E (tanh). K = (1-z)*(n - y).
__device__ __forceinline__ void gateK(const f32x4 (&gi)[3], const f32x4 (&gh)[3],
                                      const f32x4& yin, f32x4& K)
{
    f32x4 rg = rcp4(exp24(gi[0] + gh[0]) + 1.0f);
    f32x4 zc = rcp4(exp24(gi[1] + gh[1]) + 1.0f);
    f32x4 tg = 1.0f - 2.0f*rcp4(exp24(gi[2] + rg*gh[2]) + 1.0f);
    K = zc*(tg - yin);
}

__global__ void __launch_bounds__(512, 2)
fused_kernel(const float* __restrict__ pre_x, const float* __restrict__ pre_y,
             const float* __restrict__ fx,
             const float* __restrict__ W_ih, const float* __restrict__ W_hh,
             const float* __restrict__ b_ih, const float* __restrict__ b_hh,
             const float* __restrict__ W_e,  const float* __restrict__ b_e,
             const float* __restrict__ Wc_ih,const float* __restrict__ Wc_hh,
             const float* __restrict__ bc_ih,const float* __restrict__ bc_hh,
             float* __restrict__ UM,         const short* __restrict__ w1f,
             const short* __restrict__ w2f,  float* __restrict__ out)
{
    __shared__ __align__(16) short yTa[16*136];   // enc ping / RK4 y
    __shared__ __align__(16) short yTb[16*136];   // enc pong / RK4 ye1, ye3
    __shared__ __align__(16) short E1 [16*136];   // spline cp (prologue) / ye2
    __shared__ __align__(16) short xmT[16*136];
    __shared__ __align__(16) short x1T[16*136];
    __shared__ __align__(16) short UMb[16*40];
    __shared__ __align__(16) short U1b[16*40];
    __shared__ __align__(16) short oT [16*264];
    __shared__ __align__(16) short w2S[8*64*8];   // W2 A-frags resident in LDS (8 KB)

    const int tid  = threadIdx.x;
    const int w    = tid >> 6;
    const int lane = tid & 63;
    const int quad = lane >> 4;
    const int m    = lane & 15;
    const int hq   = w*16 + quad*4;
    const int b0   = blockIdx.x * 16;
    const f32x4 z4 = {0.f, 0.f, 0.f, 0.f};
    const float scg[3] = {-LOG2E, LOG2E, 2.0f*LOG2E};   // r, z(flipped), n

    for (int i = tid; i < 16*136; i += 512) yTa[i] = 0;
    for (int i = tid; i < 16*40;  i += 512) { UMb[i] = 0; U1b[i] = 0; }
    ((short8*)w2S)[tid & 511] = ((const short8*)w2f)[tid & 511];   // 512 frags, 1/thread

    f32x4 y = z4;

    // ================= encoder GRU: 1 fast barrier/step =================
    {
        short8 Ehh[3][4];
        #pragma unroll
        for (int g = 0; g < 3; ++g)
            #pragma unroll
            for (int c = 0; c < 4; ++c) {
                const float* ph = W_hh + (size_t)(g*NH + w*16 + m)*NH + c*32 + quad*8;
                short8 fh;
                #pragma unroll
                for (int j = 0; j < 8; ++j) fh[j] = f2bf(scg[g]*ph[j]);
                Ehh[g][c] = fh;
            }
        short8 Eih[3];
        #pragma unroll
        for (int g = 0; g < 3; ++g) {
            short8 f1;
            #pragma unroll
            for (int j = 0; j < 8; ++j) {
                int k = quad*8 + j;
                f1[j] = (k < 12) ? f2bf(scg[g]*W_ih[(size_t)(g*NH + w*16 + m)*12 + k]) : (short)0;
            }
            Eih[g] = f1;
        }
        f32x4 erz4, ezz4, egn4, ein4;
        #pragma unroll
        for (int r = 0; r < 4; ++r) {
            int h = hq + r;
            erz4[r] = -LOG2E*(b_ih[h]      + b_hh[h]);
            ezz4[r] =  LOG2E*(b_ih[NH + h] + b_hh[NH + h]);
            egn4[r] = 2.0f*LOG2E*b_hh[2*NH + h];
            ein4[r] = 2.0f*LOG2E*b_ih[2*NH + h];
        }
        const int eidx = w*24 + lane;
        const int eb = eidx/12, ek = eidx - 12*eb;
        const bool estg = (lane < 24);
        float encv = 0.f;
        if (estg) {
            float e0 = (ek < NKIN) ? pre_x[((size_t)0*NB + b0 + eb)*NKIN + ek]
                                   : pre_y[((size_t)0*NB + b0 + eb)*NKOUT + (ek - NKIN)];
            UMb[eb*40 + ek] = f2bf(e0);
            encv = (ek < NKIN) ? pre_x[((size_t)1*NB + b0 + eb)*NKIN + ek]
                               : pre_y[((size_t)1*NB + b0 + eb)*NKOUT + (ek - NKIN)];
        }
        BAR();
        for (int t = 0; t < NTP; ++t) {
            float evn = 0.f;
            if (estg) {
                int tn = (t + 2 < NTP) ? t + 2 : NTP - 1;
                evn = (ek < NKIN) ? pre_x[((size_t)tn*NB + b0 + eb)*NKIN + ek]
                                  : pre_y[((size_t)tn*NB + b0 + eb)*NKOUT + (ek - NKIN)];
            }
            const short* bin_buf  = (t & 1) ? U1b : UMb;
            short*       bout_buf = (t & 1) ? UMb : U1b;
            const short* sin_buf  = (t & 1) ? yTb : yTa;
            short*       sout_buf = (t & 1) ? yTa : yTb;
            f32x4 gi[3] = {z4, z4, ein4};
            {
                short8 b = *(const short8*)(bin_buf + m*40 + quad*8);
                #pragma unroll
                for (int g = 0; g < 3; ++g)
                    gi[g] = __builtin_amdgcn_mfma_f32_16x16x32_bf16(Eih[g], b, gi[g], 0, 0, 0);
            }
            f32x4 gh[3] = {erz4, ezz4, egn4};
            gemmB(sin_buf + m*136 + quad*8, Ehh, gh);
            f32x4 K;
            gateK(gi, gh, y, K);
            y += K;
            st4(sout_buf + m*136 + hq, y);
            if (estg) { bout_buf[eb*40 + ek] = f2bf(encv); encv = evn; }
            BAR();
        }
    }
    // y(0) in regs; final enc state in yTa (t=63 odd wrote yTa)

    // ---- persistent RK4 A-frags ----
    short8 Ahh[3][4], Aih[3][4];
    #pragma unroll
    for (int g = 0; g < 3; ++g)
        #pragma unroll
        for (int c = 0; c < 4; ++c) {
            const float* ph = Wc_hh + (size_t)(g*NH + w*16 + m)*NH + c*32 + quad*8;
            const float* pi = Wc_ih + (size_t)(g*NH + w*16 + m)*NH + c*32 + quad*8;
            short8 fh, fi;
            #pragma unroll
            for (int j = 0; j < 8; ++j) { fh[j] = f2bf(scg[g]*ph[j]); fi[j] = f2bf(scg[g]*pi[j]); }
            Ahh[g][c] = fh; Aih[g][c] = fi;
        }
    short8 Aexp;
    #pragma unroll
    for (int j = 0; j < 8; ++j) {
        int k = quad*8 + j;
        Aexp[j] = (k < NKIN) ? f2bf(2.0f*LOG2E*W_e[(w*16 + m)*NKIN + k]) : (short)0;
    }
    short8 A1f[2][4];
    #pragma unroll
    for (int kc = 0; kc < 4; ++kc) {
        A1f[0][kc] = *(const short8*)(w1f + (size_t)(((w    )*4 + kc)*64 + lane)*8);
        A1f[1][kc] = *(const short8*)(w1f + (size_t)(((w + 8)*4 + kc)*64 + lane)*8);
    }
    f32x4 brz4, bzz4, bgn4, bin4, be4;
    #pragma unroll
    for (int r = 0; r < 4; ++r) {
        int h = hq + r;
        brz4[r] = -LOG2E*(bc_ih[h]      + bc_hh[h]);
        bzz4[r] =  LOG2E*(bc_ih[NH + h] + bc_hh[NH + h]);
        bgn4[r] = 2.0f*LOG2E*bc_hh[2*NH + h];
        bin4[r] = 2.0f*LOG2E*bc_ih[2*NH + h];
        be4[r]  = 2.0f*LOG2E*b_e[h];
    }

    // ================= in-kernel spline (Thomas, reversed elimination) =================
    const bool stg = (lane < 16);
    const int sb = w*2 + (lane >> 3), sk = lane & 7;
    const size_t scol = (size_t)(b0 + sb)*NKIN + sk;   // only valid for stg lanes
    float* cpS = (float*)E1;
    float prex_last = 0.f;
    if (stg) prex_last = pre_x[(size_t)(NTP-1)*BKIN + scol];
    if (stg) {
        const float r6 = 6.0f/(0.1f*0.1f);
        float c = 0.f, d = 0.f;
        float yp = fx[(size_t)127*BKIN + scol];
        float y0 = fx[(size_t)126*BKIN + scol];
        float ym = fx[(size_t)125*BKIN + scol];
        #pragma unroll 4
        for (int j = 127; j >= 1; --j) {
            float r = r6*(ym - 2.f*y0 + yp);
            c = __builtin_amdgcn_rcpf(4.f - c);
            d = (r - d)*c;
            UM[(size_t)j*BKIN + scol] = d;
            if (tid == 0) cpS[128 - j] = c;
            yp = y0; y0 = ym;
            ym = (j >= 3) ? fx[(size_t)(j-3)*BKIN + scol] : prex_last;
        }
    }
    __syncthreads();   // FULL: same-thread global RAW on UM
    if (stg) {
        const float KK = 0.01f/16.0f;
        float Mp = 0.f;
        float y0 = prex_last;
        float y1 = fx[scol];
        #pragma unroll 4
        for (int j = 1; j <= 127; ++j) {
            float dj = UM[(size_t)j*BKIN + scol];
            float e  = cpS[128 - j];
            float Mj = dj - e*Mp;
            UM[(size_t)(j-1)*BKIN + scol] = 0.5f*(y0 + y1) - KK*(Mp + Mj);
            Mp = Mj; y0 = y1;
            y1 = fx[(size_t)j*BKIN + scol];
        }
        UM[(size_t)127*BKIN + scol] = 0.5f*(y0 + y1) - KK*Mp;
    }
    __syncthreads();   // FULL: UM writes drained; E1 free again

    // ================= RK4 prologue =================
    if (stg) {
        UMb[sb*40 + 8 + (lane & 3)] = 0;
        U1b[sb*40 + 8 + (lane & 3)] = 0;
        UMb[sb*40 + sk] = f2bf(prex_last);
    }
    BAR();
    {   // x0 = tanh-expand(u0_start) -> xmT
        short8 b = *(const short8*)(UMb + m*40 + quad*8);
        f32x4 c0 = be4;
        c0 = __builtin_amdgcn_mfma_f32_16x16x32_bf16(Aexp, b, c0, 0, 0, 0);
        f32x4 xv = 1.0f - 2.0f*rcp4(exp24(c0) + 1.0f);
        st4(xmT + m*136 + hq, xv);
    }
    BAR();
    f32x4 gi0[3] = {z4, z4, bin4};
    gemmB(xmT + m*136 + quad*8, Aih, gi0);
    if (stg) { UMb[sb*40 + sk] = f2bf(UM[scol]); U1b[sb*40 + sk] = f2bf(fx[scol]); }
    BAR();
    {   // expand u(0) -> xmT, x1T
        short8 bm = *(const short8*)(UMb + m*40 + quad*8);
        short8 b1 = *(const short8*)(U1b + m*40 + quad*8);
        f32x4 cm = be4, c1 = be4;
        cm = __builtin_amdgcn_mfma_f32_16x16x32_bf16(Aexp, bm, cm, 0, 0, 0);
        c1 = __builtin_amdgcn_mfma_f32_16x16x32_bf16(Aexp, b1, c1, 0, 0, 0);
        f32x4 xm = 1.0f - 2.0f*rcp4(exp24(cm) + 1.0f);
        f32x4 x1 = 1.0f - 2.0f*rcp4(exp24(c1) + 1.0f);
        st4(xmT + m*136 + hq, xm);
        st4(x1T + m*136 + hq, x1);
    }
    float fxv = 0.f, umv = 0.f;
    if (stg) { fxv = fx[(size_t)BKIN + scol]; umv = UM[(size_t)BKIN + scol]; }  // u(1)
    BAR();
    f32x4 gim[3] = {z4, z4, bin4}, gi1[3] = {z4, z4, bin4};
    gemmB(xmT + m*136 + quad*8, Aih, gim);
    gemmB(x1T + m*136 + quad*8, Aih, gi1);

    // ================= RK4 loop: 4 fast barriers/step =================
    // P1 = k1 + head1(st-1) | P2 = k2 + stage2(st-1) + staging u(st+1)
    // P3 = k3 + expand(st+1) | P4 = k4 + y-upd + gim/gi1(st+1) + prefetch u(st+2)
    for (int st = 0; st < NL; ++st) {
        // ---- P1: k1 + head1(st-1) (shared yTa read) ----
        short8 byf[4];
        ld4(yTa + m*136 + quad*8, byf);
        f32x4 gh[3] = {brz4, bzz4, bgn4};
        gemmR(byf, Ahh, gh);
        if (st > 0) {
            f32x4 o0 = z4, o1 = z4;
            #pragma unroll
            for (int kc = 0; kc < 4; ++kc) {
                o0 = __builtin_amdgcn_mfma_f32_16x16x32_bf16(A1f[0][kc], byf[kc], o0, 0, 0, 0);
                o1 = __builtin_amdgcn_mfma_f32_16x16x32_bf16(A1f[1][kc], byf[kc], o1, 0, 0, 0);
            }
            f32x4 t0 = 1.0f - 2.0f*rcp4(exp24(o0) + 1.0f);
            f32x4 t1 = 1.0f - 2.0f*rcp4(exp24(o1) + 1.0f);
            st4(oT + m*264 + w*16     + quad*4, t0);
            st4(oT + m*264 + (w+8)*16 + quad*4, t1);
        }
        f32x4 K, Ks, ye;
        gateK(gi0, gh, y, K);
        Ks = K; ye = y + 0.5f*K;
        st4(yTb + m*136 + hq, ye);
        BAR();                                                  // B1
        // ---- P2: k2 + stage2(st-1) + staging u(st+1) ----
        if (stg) { UMb[sb*40 + sk] = f2bf(umv); U1b[sb*40 + sk] = f2bf(fxv); }
        gh[0] = brz4; gh[1] = bzz4; gh[2] = bgn4;
        gemmB(yTb + m*136 + quad*8, Ahh, gh);
        if (st > 0 && w == ((st-1) & 7)) {
            f32x4 oc = z4;
            #pragma unroll
            for (int kc = 0; kc < 8; ++kc) {
                short8 a2 = *(const short8*)(w2S + (kc*64 + lane)*8);
                short8 b  = *(const short8*)(oT + m*264 + kc*32 + quad*8);
                oc = __builtin_amdgcn_mfma_f32_16x16x32_bf16(a2, b, oc, 0, 0, 0);
            }
            if (quad == 0)
                *(f32x4*)(out + ((size_t)(st-1)*NB + b0 + m)*NKOUT) = oc;
        }
        gateK(gim, gh, ye, K);
        Ks += 2.0f*K; ye = y + 0.5f*K;
        st4(E1 + m*136 + hq, ye);
        BAR();                                                  // B2
        // ---- P3: k3 + expand(st+1) ----
        gh[0] = brz4; gh[1] = bzz4; gh[2] = bgn4;
        gemmB(E1 + m*136 + quad*8, Ahh, gh);
        {
            short8 bm = *(const short8*)(UMb + m*40 + quad*8);
            short8 b1 = *(const short8*)(U1b + m*40 + quad*8);
            f32x4 cm = be4, c1 = be4;
            cm = __builtin_amdgcn_mfma_f32_16x16x32_bf16(Aexp, bm, cm, 0, 0, 0);
            c1 = __builtin_amdgcn_mfma_f32_16x16x32_bf16(Aexp, b1, c1, 0, 0, 0);
            f32x4 xm = 1.0f - 2.0f*rcp4(exp24(cm) + 1.0f);
            f32x4 x1 = 1.0f - 2.0f*rcp4(exp24(c1) + 1.0f);
            st4(xmT + m*136 + hq, xm);
            st4(x1T + m*136 + hq, x1);
        }
        gateK(gim, gh, ye, K);
        Ks += 2.0f*K; ye = y + K;
        st4(yTb + m*136 + hq, ye);
        BAR();                                                  // B3
        // ---- P4: k4 + y update + gim/gi1(st+1) + prefetch u(st+2) ----
        if (stg) {
            int sn = (st + 2 < NL) ? st + 2 : NL - 1;
            fxv = fx[(size_t)sn*BKIN + scol];
            umv = UM[(size_t)sn*BKIN + scol];
        }
        gh[0] = brz4; gh[1] = bzz4; gh[2] = bgn4;
        gemmB(yTb + m*136 + quad*8, Ahh, gh);
        gateK(gi1, gh, ye, K);
        y += (1.0f/6.0f)*(Ks + K);
        st4(yTa + m*136 + hq, y);
        gi0[0] = gi1[0]; gi0[1] = gi1[1]; gi0[2] = gi1[2];
        gim[0] = z4; gim[1] = z4; gim[2] = bin4;
        gi1[0] = z4; gi1[1] = z4; gi1[2] = bin4;
        gemmB(xmT + m*136 + quad*8, Aih, gim);
        gemmB(x1T + m*136 + quad*8, Aih, gi1);
        BAR();                                                  // B4
    }

    // ================= epilogue: head + stage2 for out[127] =================
    {
        short8 byf[4];
        ld4(yTa + m*136 + quad*8, byf);
        f32x4 o0 = z4, o1 = z4;
        #pragma unroll
        for (int kc = 0; kc < 4; ++kc) {
            o0 = __builtin_amdgcn_mfma_f32_16x16x32_bf16(A1f[0][kc], byf[kc], o0, 0, 0, 0);
            o1 = __builtin_amdgcn_mfma_f32_16x16x32_bf16(A1f[1][kc], byf[kc], o1, 0, 0, 0);
        }
        f32x4 t0 = 1.0f - 2.0f*rcp4(exp24(o0) + 1.0f);
        f32x4 t1 = 1.0f - 2.0f*rcp4(exp24(o1) + 1.0f);
        st4(oT + m*264 + w*16     + quad*4, t0);
        st4(oT + m*264 + (w+8)*16 + quad*4, t1);
        BAR();
        if (w == 7) {
            f32x4 oc = z4;
            #pragma unroll
            for (int kc = 0; kc < 8; ++kc) {
                short8 a2 = *(const short8*)(w2S + (kc*64 + lane)*8);
                short8 b  = *(const short8*)(oT + m*264 + kc*32 + quad*8);
                oc = __builtin_amdgcn_mfma_f32_16x16x32_bf16(a2, b, oc, 0, 0, 0);
            }
            if (quad == 0)
                *(f32x4*)(out + ((size_t)(NL-1)*NB + b0 + m)*NKOUT) = oc;
        }
    }
}

extern "C" void kernel_launch(void* const* d_in, const int* in_sizes, int n_in,
                              void* d_out, int out_size, void* d_ws, size_t ws_size,
                              hipStream_t stream)
{
    const float* pre_x = (const float*)d_in[0];
    const float* pre_y = (const float*)d_in[1];
    const float* fx    = (const float*)d_in[2];
    const float* W_ih  = (const float*)d_in[3];
    const float* W_hh  = (const float*)d_in[4];
    const float* b_ih  = (const float*)d_in[5];
    const float* b_hh  = (const float*)d_in[6];
    const float* W_e   = (const float*)d_in[7];
    const float* b_e   = (const float*)d_in[8];
    const float* Wc_ih = (const float*)d_in[9];
    const float* Wc_hh = (const float*)d_in[10];
    const float* bc_ih = (const float*)d_in[11];
    const float* bc_hh = (const float*)d_in[12];
    const float* W1    = (const float*)d_in[13];
    const float* W2    = (const float*)d_in[14];
    float* out = (float*)d_out;

    float* UM  = (float*)d_ws;                                  // 128*4096*8 fp32 = 16.78 MB
    short* w1f = (short*)((char*)d_ws + (size_t)NL*NB*NKIN*4);  // 32768 shorts
    short* w2f = w1f + 16*4*64*8;                               // 4096 shorts

    prep_frags<<<dim3(8), dim3(256), 0, stream>>>(W1, W2, w1f, w2f);
    fused_kernel<<<dim3(NB/16), dim3(512), 0, stream>>>(
        pre_x, pre_y, fx, W_ih, W_hh, b_ih, b_hh, W_e, b_e,
        Wc_ih, Wc_hh, bc_ih, bc_hh, UM, w1f, w2f, out);
}